// Round 10
// baseline (226.435 us; speedup 1.0000x reference)
//
#include <hip/hip_runtime.h>
#include <math.h>

#define NB 16
#define NH 512
#define NW 512
#define NHW (NH * NW)
#define LAM2 0.01f
#define TOLV 0.001f
#define MAXIT 10
#define ROWS 8                  // rows per block strip
#define RPW 2                   // rows per wave (4 waves/block)
#define NCHUNK (NH / ROWS)      // 64 strips per batch
#define NTHREADS 256
#define COMP_STRIDE (NB * NCHUNK)

#define PARTIALS_N (5 * NB * NCHUNK)
#define PWS_OFF (PARTIALS_N * 8)
#define ERR_OFF (PWS_OFF + 32 * 4)

__device__ __forceinline__ float cubicf(float t) {
    float a = fabsf(t);
    float a2 = a * a;
    float a3 = a2 * a;
    if (a <= 1.0f) return 1.5f * a3 - 2.5f * a2 + 1.0f;
    if (a < 2.0f)  return -0.5f * a3 + 2.5f * a2 - 4.0f * a + 2.0f;
    return 0.0f;
}

__device__ __forceinline__ int clampy(int v) { return min(max(v, 0), NH - 1); }
__device__ __forceinline__ int clampx(int v) { return min(max(v, 0), NW - 1); }

__device__ __forceinline__ float4 L4(const float* __restrict__ p, int row, int i) {
    return ((const float4*)(p + (size_t)row * NW))[i];
}

__device__ __forceinline__ void unpack8(const float4& A, const float4& B, float* o) {
    o[0] = A.x; o[1] = A.y; o[2] = A.z; o[3] = A.w;
    o[4] = B.x; o[5] = B.y; o[6] = B.z; o[7] = B.w;
}

__global__ __launch_bounds__(64) void gn_init(const float* __restrict__ p_in,
                                              float* __restrict__ pws,
                                              float* __restrict__ errws) {
    int t = threadIdx.x;
    if (t < 2 * NB) pws[t] = p_in[t];
    if (t == 0) errws[0] = 1e10f;
}

// Wave-private rows: each wave owns RPW full rows; zero barriers in main loop.
// Lane covers 8 cols; V kept in a per-wave LDS row with replicated-edge halo.
__global__ __launch_bounds__(NTHREADS) void gn_reduce(const float* __restrict__ I1,
                                                      const float* __restrict__ I2,
                                                      const float* __restrict__ pws,
                                                      double* __restrict__ partials) {
    const int b = blockIdx.y;
    const int strip = blockIdx.x;
    const int tid = threadIdx.x;
    const int wv = tid >> 6, lane = tid & 63;
    const int c0 = 8 * lane;
    const float tx = pws[2 * b];
    const float ty = pws[2 * b + 1];
    const float* I1b = I1 + (size_t)b * NHW;
    const float* I2b = I2 + (size_t)b * NHW;

    // ---- horizontal setup: weights once per lane, exact per-col floor check ----
    float gx0 = (float)c0 + tx;
    float fx0 = floorf(gx0);
    float dx0 = gx0 - fx0;
    int x00 = (int)fx0;
    const float wx0 = cubicf(dx0 + 1.0f), wx1 = cubicf(dx0);
    const float wx2 = cubicf(dx0 - 1.0f), wx3 = cubicf(dx0 - 2.0f);
    bool fast = true;
#pragma unroll
    for (int j = 1; j < 8; ++j) {
        int xj = (int)floorf((float)(c0 + j) + tx);
        fast = fast && (xj == x00 + j);
    }
    const int base = x00 - 1;                 // taps span base..base+10
    fast = fast && (base >= -8) && (base + 10 <= NW + 7);   // inside halo
    const int s = base & 3;
    const int wbase = base - s;               // 4-aligned

    __shared__ float VS[4][NW + 24];          // [wave][8 halo | 512 | 8 halo | pad]
    float* Vw = VS[wv];

    const int ybase = strip * ROWS + wv * RPW;

    // vertical taps for first row
    int yj0, yj1, yj2, yj3;
    {
        int yy = (int)floorf((float)ybase + ty);
        yj0 = clampy(yy - 1); yj1 = clampy(yy);
        yj2 = clampy(yy + 1); yj3 = clampy(yy + 2);
    }
    float4 w0a = L4(I2b, yj0, 2 * lane), w0b = L4(I2b, yj0, 2 * lane + 1);
    float4 w1a = L4(I2b, yj1, 2 * lane), w1b = L4(I2b, yj1, 2 * lane + 1);
    float4 w2a = L4(I2b, yj2, 2 * lane), w2b = L4(I2b, yj2, 2 * lane + 1);
    float4 w3a = L4(I2b, yj3, 2 * lane), w3b = L4(I2b, yj3, 2 * lane + 1);

    // I1 rolling rows
    float4 cpa = L4(I1b, max(ybase - 1, 0), 2 * lane), cpb = L4(I1b, max(ybase - 1, 0), 2 * lane + 1);
    float4 cca = L4(I1b, ybase, 2 * lane),             ccb = L4(I1b, ybase, 2 * lane + 1);
    float4 cna = L4(I1b, min(ybase + 1, NH - 1), 2 * lane), cnb = L4(I1b, min(ybase + 1, NH - 1), 2 * lane + 1);

    float a0 = 0.f, a1 = 0.f, a2 = 0.f, a3 = 0.f, a4 = 0.f;

#pragma unroll
    for (int r = 0; r < RPW; ++r) {
        const int y = ybase + r;

        // wy weights (per-lane, redundant, no LDS)
        float gy = (float)y + ty, fy = floorf(gy), dy = gy - fy;
        const float wy0 = cubicf(dy + 1.0f), wy1 = cubicf(dy);
        const float wy2 = cubicf(dy - 1.0f), wy3 = cubicf(dy - 2.0f);

        // next-row taps + prefetch (issued early, consumed at roll)
        int nyj0 = 0, nyj1 = 0, nyj2 = 0, nyj3 = 0;
        bool aligned = true;
        float4 nta, ntb, n1a, n1b;
        if (r + 1 < RPW) {
            int yy2 = (int)floorf((float)(y + 1) + ty);
            nyj0 = clampy(yy2 - 1); nyj1 = clampy(yy2);
            nyj2 = clampy(yy2 + 1); nyj3 = clampy(yy2 + 2);
            aligned = (nyj0 == yj1) && (nyj1 == yj2) && (nyj2 == yj3);
            nta = L4(I2b, nyj3, 2 * lane); ntb = L4(I2b, nyj3, 2 * lane + 1);
            n1a = L4(I1b, min(y + 2, NH - 1), 2 * lane);
            n1b = L4(I1b, min(y + 2, NH - 1), 2 * lane + 1);
        }

        // vertical combine -> wave-private LDS (+ halo)
        float4 Va, Vb;
        Va.x = wy0 * w0a.x + wy1 * w1a.x + wy2 * w2a.x + wy3 * w3a.x;
        Va.y = wy0 * w0a.y + wy1 * w1a.y + wy2 * w2a.y + wy3 * w3a.y;
        Va.z = wy0 * w0a.z + wy1 * w1a.z + wy2 * w2a.z + wy3 * w3a.z;
        Va.w = wy0 * w0a.w + wy1 * w1a.w + wy2 * w2a.w + wy3 * w3a.w;
        Vb.x = wy0 * w0b.x + wy1 * w1b.x + wy2 * w2b.x + wy3 * w3b.x;
        Vb.y = wy0 * w0b.y + wy1 * w1b.y + wy2 * w2b.y + wy3 * w3b.y;
        Vb.z = wy0 * w0b.z + wy1 * w1b.z + wy2 * w2b.z + wy3 * w3b.z;
        Vb.w = wy0 * w0b.w + wy1 * w1b.w + wy2 * w2b.w + wy3 * w3b.w;
        ((float4*)(Vw + 8))[2 * lane] = Va;
        ((float4*)(Vw + 8))[2 * lane + 1] = Vb;
        if (lane == 0)  { float4 h; h.x = h.y = h.z = h.w = Va.x; ((float4*)Vw)[0] = h; ((float4*)Vw)[1] = h; }
        if (lane == 63) { float4 h; h.x = h.y = h.z = h.w = Vb.w; ((float4*)(Vw + 8 + NW))[0] = h; ((float4*)(Vw + 8 + NW))[1] = h; }

        // I1 gradients (registers + in-wave shfl; row edges are wave edges)
        float left = __shfl_up(ccb.w, 1);
        float right = __shfl_down(cca.x, 1);
        float cc[8], cp[8], cn[8];
        unpack8(cca, ccb, cc); unpack8(cpa, cpb, cp); unpack8(cna, cnb, cn);
        float Ix[8], Iy[8];
        Ix[0] = (lane > 0) ? 0.5f * (cc[1] - left) : 0.0f;
#pragma unroll
        for (int j = 1; j < 7; ++j) Ix[j] = 0.5f * (cc[j + 1] - cc[j - 1]);
        Ix[7] = (lane < 63) ? 0.5f * (right - cc[6]) : 0.0f;
        const bool yint = (y >= 1 && y <= NH - 2);
#pragma unroll
        for (int j = 0; j < 8; ++j) Iy[j] = yint ? 0.5f * (cn[j] - cp[j]) : 0.0f;

        // horizontal pass (same-wave LDS round-trip, lgkmcnt only)
        float Hc[8];
        if (fast) {
            const float4* Wp = (const float4*)(Vw + 8 + wbase);
            float4 W0 = Wp[0], W1 = Wp[1], W2 = Wp[2], W3 = Wp[3];
            float u0, u1, u2, u3, u4, u5, u6, u7, u8, u9, u10;
            switch (s) {
                case 0:  u0=W0.x; u1=W0.y; u2=W0.z; u3=W0.w; u4=W1.x; u5=W1.y; u6=W1.z; u7=W1.w; u8=W2.x; u9=W2.y; u10=W2.z; break;
                case 1:  u0=W0.y; u1=W0.z; u2=W0.w; u3=W1.x; u4=W1.y; u5=W1.z; u6=W1.w; u7=W2.x; u8=W2.y; u9=W2.z; u10=W2.w; break;
                case 2:  u0=W0.z; u1=W0.w; u2=W1.x; u3=W1.y; u4=W1.z; u5=W1.w; u6=W2.x; u7=W2.y; u8=W2.z; u9=W2.w; u10=W3.x; break;
                default: u0=W0.w; u1=W1.x; u2=W1.y; u3=W1.z; u4=W1.w; u5=W2.x; u6=W2.y; u7=W2.z; u8=W2.w; u9=W3.x; u10=W3.y; break;
            }
            Hc[0] = wx0*u0 + wx1*u1 + wx2*u2  + wx3*u3;
            Hc[1] = wx0*u1 + wx1*u2 + wx2*u3  + wx3*u4;
            Hc[2] = wx0*u2 + wx1*u3 + wx2*u4  + wx3*u5;
            Hc[3] = wx0*u3 + wx1*u4 + wx2*u5  + wx3*u6;
            Hc[4] = wx0*u4 + wx1*u5 + wx2*u6  + wx3*u7;
            Hc[5] = wx0*u5 + wx1*u6 + wx2*u7  + wx3*u8;
            Hc[6] = wx0*u6 + wx1*u7 + wx2*u8  + wx3*u9;
            Hc[7] = wx0*u7 + wx1*u8 + wx2*u9  + wx3*u10;
        } else {
            // exact per-col slow path (floor-flip lanes; rare)
#pragma unroll
            for (int j = 0; j < 8; ++j) {
                float g = (float)(c0 + j) + tx;
                float f = floorf(g);
                int x0 = (int)f;
                float d = g - f;
                float v0 = cubicf(d + 1.0f), v1 = cubicf(d);
                float v2 = cubicf(d - 1.0f), v3 = cubicf(d - 2.0f);
                Hc[j] = v0 * Vw[8 + clampx(x0 - 1)] + v1 * Vw[8 + clampx(x0)] +
                        v2 * Vw[8 + clampx(x0 + 1)] + v3 * Vw[8 + clampx(x0 + 2)];
            }
        }

        // robust stats (f32 inner accumulation, widened at reduce)
#pragma unroll
        for (int j = 0; j < 8; ++j) {
            float DI = Hc[j] - cc[j];
            float rho = 1.0f / sqrtf(DI * DI + LAM2);
            float dr = DI * rho;
            a0 += Ix[j] * Ix[j] * rho;
            a1 += Ix[j] * Iy[j] * rho;
            a2 += Iy[j] * Iy[j] * rho;
            a3 += Ix[j] * dr;
            a4 += Iy[j] * dr;
        }

        // roll windows
        if (r + 1 < RPW) {
            if (aligned) {
                w0a = w1a; w0b = w1b; w1a = w2a; w1b = w2b; w2a = w3a; w2b = w3b;
            } else {          // border strips only
                w0a = L4(I2b, nyj0, 2 * lane); w0b = L4(I2b, nyj0, 2 * lane + 1);
                w1a = L4(I2b, nyj1, 2 * lane); w1b = L4(I2b, nyj1, 2 * lane + 1);
                w2a = L4(I2b, nyj2, 2 * lane); w2b = L4(I2b, nyj2, 2 * lane + 1);
            }
            w3a = nta; w3b = ntb;
            yj0 = nyj0; yj1 = nyj1; yj2 = nyj2; yj3 = nyj3;
            cpa = cca; cpb = ccb; cca = cna; ccb = cnb; cna = n1a; cnb = n1b;
        }
    }

    // widen to f64, wave butterfly, cross-wave via LDS (single barrier)
    double d0 = a0, d1 = a1, d2 = a2, d3 = a3, d4 = a4;
#pragma unroll
    for (int off = 32; off > 0; off >>= 1) {
        d0 += __shfl_down(d0, off);
        d1 += __shfl_down(d1, off);
        d2 += __shfl_down(d2, off);
        d3 += __shfl_down(d3, off);
        d4 += __shfl_down(d4, off);
    }
    __shared__ double wsum[4][5];
    if (lane == 0) {
        wsum[wv][0] = d0; wsum[wv][1] = d1; wsum[wv][2] = d2;
        wsum[wv][3] = d3; wsum[wv][4] = d4;
    }
    __syncthreads();
    if (tid < 5) {
        double ssum = wsum[0][tid] + wsum[1][tid] + wsum[2][tid] + wsum[3][tid];
        partials[(size_t)tid * COMP_STRIDE + b * NCHUNK + strip] = ssum;
    }
}

__global__ __launch_bounds__(128) void gn_update(const double* __restrict__ partials,
                                                 float* __restrict__ pws,
                                                 float* __restrict__ errws,
                                                 float* __restrict__ out,
                                                 int write_out) {
    __shared__ double Hs[NB][5];
    __shared__ float dpf[NB][2];
    __shared__ float pnew[2 * NB];
    const int tid = threadIdx.x;

    if (tid < NB * 5) {
        int bb = tid & 15, comp = tid >> 4;
        const double* src = partials + (size_t)comp * COMP_STRIDE + bb * NCHUNK;
        double s = 0;
#pragma unroll 8
        for (int ch = 0; ch < NCHUNK; ++ch) s += src[ch];
        Hs[bb][comp] = s;
    }
    __syncthreads();

    if (tid < NB) {
        double H00 = Hs[tid][0], H01 = Hs[tid][1], H11 = Hs[tid][2];
        double b0 = Hs[tid][3], b1 = Hs[tid][4];
        double inv = 1.0 / (H00 * H11 - H01 * H01);
        double dp0 = ( H11 * b0 - H01 * b1) * inv;
        double dp1 = (-H01 * b0 + H00 * b1) * inv;
        dpf[tid][0] = (float)dp0;
        dpf[tid][1] = (float)dp1;
    }
    __syncthreads();

    float err_old = errws[0];
    bool active = err_old > TOLV;

    if (tid < 2 * NB) {
        float pv = pws[tid];
        if (active) pv -= dpf[tid >> 1][tid & 1];
        pnew[tid] = pv;
        pws[tid] = pv;
    }

    float err_new = err_old;
    if (tid == 0) {
        if (active) {
            double n = 0;
            for (int i = 0; i < NB; ++i) {
                n += (double)dpf[i][0] * (double)dpf[i][0];
                n += (double)dpf[i][1] * (double)dpf[i][1];
            }
            err_new = (float)sqrt(n);
            errws[0] = err_new;
        }
    }
    __syncthreads();
    if (write_out) {
        if (tid < 2 * NB) out[tid] = pnew[tid];
        if (tid == 0) out[2 * NB] = err_new;
    }
}

// Barrier-free final warp: same structure, no stats, float4 stores.
__global__ __launch_bounds__(NTHREADS) void gn_final(const float* __restrict__ I1,
                                                     const float* __restrict__ I2,
                                                     const float* __restrict__ pws,
                                                     float* __restrict__ out) {
    const int b = blockIdx.y;
    const int strip = blockIdx.x;
    const int tid = threadIdx.x;
    const int wv = tid >> 6, lane = tid & 63;
    const int c0 = 8 * lane;
    const float tx = pws[2 * b];
    const float ty = pws[2 * b + 1];
    const float* I1b = I1 + (size_t)b * NHW;
    const float* I2b = I2 + (size_t)b * NHW;

    float* DIout = out + 33;
    float* IWout = out + 33 + (size_t)NB * NHW;

    float gx0 = (float)c0 + tx;
    float fx0 = floorf(gx0);
    float dx0 = gx0 - fx0;
    int x00 = (int)fx0;
    const float wx0 = cubicf(dx0 + 1.0f), wx1 = cubicf(dx0);
    const float wx2 = cubicf(dx0 - 1.0f), wx3 = cubicf(dx0 - 2.0f);
    bool fast = true;
#pragma unroll
    for (int j = 1; j < 8; ++j) {
        int xj = (int)floorf((float)(c0 + j) + tx);
        fast = fast && (xj == x00 + j);
    }
    const int base = x00 - 1;
    fast = fast && (base >= -8) && (base + 10 <= NW + 7);
    const int s = base & 3;
    const int wbase = base - s;

    __shared__ float VS[4][NW + 24];
    float* Vw = VS[wv];

    const int ybase = strip * ROWS + wv * RPW;

    int yj0, yj1, yj2, yj3;
    {
        int yy = (int)floorf((float)ybase + ty);
        yj0 = clampy(yy - 1); yj1 = clampy(yy);
        yj2 = clampy(yy + 1); yj3 = clampy(yy + 2);
    }
    float4 w0a = L4(I2b, yj0, 2 * lane), w0b = L4(I2b, yj0, 2 * lane + 1);
    float4 w1a = L4(I2b, yj1, 2 * lane), w1b = L4(I2b, yj1, 2 * lane + 1);
    float4 w2a = L4(I2b, yj2, 2 * lane), w2b = L4(I2b, yj2, 2 * lane + 1);
    float4 w3a = L4(I2b, yj3, 2 * lane), w3b = L4(I2b, yj3, 2 * lane + 1);
    float4 cca = L4(I1b, ybase, 2 * lane), ccb = L4(I1b, ybase, 2 * lane + 1);

#pragma unroll
    for (int r = 0; r < RPW; ++r) {
        const int y = ybase + r;

        float gy = (float)y + ty, fy = floorf(gy), dy = gy - fy;
        const float wy0 = cubicf(dy + 1.0f), wy1 = cubicf(dy);
        const float wy2 = cubicf(dy - 1.0f), wy3 = cubicf(dy - 2.0f);

        int nyj0 = 0, nyj1 = 0, nyj2 = 0, nyj3 = 0;
        bool aligned = true;
        float4 nta, ntb, n1a, n1b;
        if (r + 1 < RPW) {
            int yy2 = (int)floorf((float)(y + 1) + ty);
            nyj0 = clampy(yy2 - 1); nyj1 = clampy(yy2);
            nyj2 = clampy(yy2 + 1); nyj3 = clampy(yy2 + 2);
            aligned = (nyj0 == yj1) && (nyj1 == yj2) && (nyj2 == yj3);
            nta = L4(I2b, nyj3, 2 * lane); ntb = L4(I2b, nyj3, 2 * lane + 1);
            n1a = L4(I1b, y + 1, 2 * lane); n1b = L4(I1b, y + 1, 2 * lane + 1);
        }

        float4 Va, Vb;
        Va.x = wy0 * w0a.x + wy1 * w1a.x + wy2 * w2a.x + wy3 * w3a.x;
        Va.y = wy0 * w0a.y + wy1 * w1a.y + wy2 * w2a.y + wy3 * w3a.y;
        Va.z = wy0 * w0a.z + wy1 * w1a.z + wy2 * w2a.z + wy3 * w3a.z;
        Va.w = wy0 * w0a.w + wy1 * w1a.w + wy2 * w2a.w + wy3 * w3a.w;
        Vb.x = wy0 * w0b.x + wy1 * w1b.x + wy2 * w2b.x + wy3 * w3b.x;
        Vb.y = wy0 * w0b.y + wy1 * w1b.y + wy2 * w2b.y + wy3 * w3b.y;
        Vb.z = wy0 * w0b.z + wy1 * w1b.z + wy2 * w2b.z + wy3 * w3b.z;
        Vb.w = wy0 * w0b.w + wy1 * w1b.w + wy2 * w2b.w + wy3 * w3b.w;
        ((float4*)(Vw + 8))[2 * lane] = Va;
        ((float4*)(Vw + 8))[2 * lane + 1] = Vb;
        if (lane == 0)  { float4 h; h.x = h.y = h.z = h.w = Va.x; ((float4*)Vw)[0] = h; ((float4*)Vw)[1] = h; }
        if (lane == 63) { float4 h; h.x = h.y = h.z = h.w = Vb.w; ((float4*)(Vw + 8 + NW))[0] = h; ((float4*)(Vw + 8 + NW))[1] = h; }

        float Hc[8];
        if (fast) {
            const float4* Wp = (const float4*)(Vw + 8 + wbase);
            float4 W0 = Wp[0], W1 = Wp[1], W2 = Wp[2], W3 = Wp[3];
            float u0, u1, u2, u3, u4, u5, u6, u7, u8, u9, u10;
            switch (s) {
                case 0:  u0=W0.x; u1=W0.y; u2=W0.z; u3=W0.w; u4=W1.x; u5=W1.y; u6=W1.z; u7=W1.w; u8=W2.x; u9=W2.y; u10=W2.z; break;
                case 1:  u0=W0.y; u1=W0.z; u2=W0.w; u3=W1.x; u4=W1.y; u5=W1.z; u6=W1.w; u7=W2.x; u8=W2.y; u9=W2.z; u10=W2.w; break;
                case 2:  u0=W0.z; u1=W0.w; u2=W1.x; u3=W1.y; u4=W1.z; u5=W1.w; u6=W2.x; u7=W2.y; u8=W2.z; u9=W2.w; u10=W3.x; break;
                default: u0=W0.w; u1=W1.x; u2=W1.y; u3=W1.z; u4=W1.w; u5=W2.x; u6=W2.y; u7=W2.z; u8=W2.w; u9=W3.x; u10=W3.y; break;
            }
            Hc[0] = wx0*u0 + wx1*u1 + wx2*u2  + wx3*u3;
            Hc[1] = wx0*u1 + wx1*u2 + wx2*u3  + wx3*u4;
            Hc[2] = wx0*u2 + wx1*u3 + wx2*u4  + wx3*u5;
            Hc[3] = wx0*u3 + wx1*u4 + wx2*u5  + wx3*u6;
            Hc[4] = wx0*u4 + wx1*u5 + wx2*u6  + wx3*u7;
            Hc[5] = wx0*u5 + wx1*u6 + wx2*u7  + wx3*u8;
            Hc[6] = wx0*u6 + wx1*u7 + wx2*u8  + wx3*u9;
            Hc[7] = wx0*u7 + wx1*u8 + wx2*u9  + wx3*u10;
        } else {
#pragma unroll
            for (int j = 0; j < 8; ++j) {
                float g = (float)(c0 + j) + tx;
                float f = floorf(g);
                int x0 = (int)f;
                float d = g - f;
                float v0 = cubicf(d + 1.0f), v1 = cubicf(d);
                float v2 = cubicf(d - 1.0f), v3 = cubicf(d - 2.0f);
                Hc[j] = v0 * Vw[8 + clampx(x0 - 1)] + v1 * Vw[8 + clampx(x0)] +
                        v2 * Vw[8 + clampx(x0 + 1)] + v3 * Vw[8 + clampx(x0 + 2)];
            }
        }

        float cc[8];
        unpack8(cca, ccb, cc);
        float4 dA, dB, wA, wB;
        dA.x = Hc[0] - cc[0]; dA.y = Hc[1] - cc[1]; dA.z = Hc[2] - cc[2]; dA.w = Hc[3] - cc[3];
        dB.x = Hc[4] - cc[4]; dB.y = Hc[5] - cc[5]; dB.z = Hc[6] - cc[6]; dB.w = Hc[7] - cc[7];
        wA.x = Hc[0]; wA.y = Hc[1]; wA.z = Hc[2]; wA.w = Hc[3];
        wB.x = Hc[4]; wB.y = Hc[5]; wB.z = Hc[6]; wB.w = Hc[7];
        size_t o = (size_t)b * NHW + (size_t)y * NW + c0;
        *(float4*)(DIout + o) = dA; *(float4*)(DIout + o + 4) = dB;
        *(float4*)(IWout + o) = wA; *(float4*)(IWout + o + 4) = wB;

        if (r + 1 < RPW) {
            if (aligned) {
                w0a = w1a; w0b = w1b; w1a = w2a; w1b = w2b; w2a = w3a; w2b = w3b;
            } else {
                w0a = L4(I2b, nyj0, 2 * lane); w0b = L4(I2b, nyj0, 2 * lane + 1);
                w1a = L4(I2b, nyj1, 2 * lane); w1b = L4(I2b, nyj1, 2 * lane + 1);
                w2a = L4(I2b, nyj2, 2 * lane); w2b = L4(I2b, nyj2, 2 * lane + 1);
            }
            w3a = nta; w3b = ntb;
            yj0 = nyj0; yj1 = nyj1; yj2 = nyj2; yj3 = nyj3;
            cca = n1a; ccb = n1b;
        }
    }
}

extern "C" void kernel_launch(void* const* d_in, const int* in_sizes, int n_in,
                              void* d_out, int out_size, void* d_ws, size_t ws_size,
                              hipStream_t stream) {
    const float* I1 = (const float*)d_in[0];
    const float* I2 = (const float*)d_in[1];
    const float* p  = (const float*)d_in[2];
    float* out = (float*)d_out;

    double* partials = (double*)d_ws;
    float* pws   = (float*)((char*)d_ws + PWS_OFF);
    float* errws = (float*)((char*)d_ws + ERR_OFF);

    gn_init<<<1, 64, 0, stream>>>(p, pws, errws);

    dim3 grid(NH / ROWS, NB);
    for (int t = 0; t < MAXIT; ++t) {
        gn_reduce<<<grid, NTHREADS, 0, stream>>>(I1, I2, pws, partials);
        gn_update<<<1, 128, 0, stream>>>(partials, pws, errws, out, (t == MAXIT - 1) ? 1 : 0);
    }
    gn_final<<<grid, NTHREADS, 0, stream>>>(I1, I2, pws, out);
}

// Round 11
// 181.426 us; speedup vs baseline: 1.2481x; 1.2481x over previous
//
#include <hip/hip_runtime.h>
#include <math.h>

#define NB 16
#define NH 512
#define NW 512
#define NHW (NH * NW)
#define LAM2 0.01f
#define TOLV 0.001f
#define MAXIT 10
#define ROWS 16                 // rows per block strip
#define RPW 4                   // rows per wave (4 waves/block)
#define NCHUNK (NH / ROWS)      // 32 strips per batch
#define NTHREADS 256
#define COMP_STRIDE (NB * NCHUNK)

#define PARTIALS_N (5 * NB * NCHUNK)
#define PWS_OFF (PARTIALS_N * 8)
#define ERR_OFF (PWS_OFF + 32 * 4)

__device__ __forceinline__ float cubicf(float t) {
    float a = fabsf(t);
    float a2 = a * a;
    float a3 = a2 * a;
    if (a <= 1.0f) return 1.5f * a3 - 2.5f * a2 + 1.0f;
    if (a < 2.0f)  return -0.5f * a3 + 2.5f * a2 - 4.0f * a + 2.0f;
    return 0.0f;
}

__device__ __forceinline__ int clampy(int v) { return min(max(v, 0), NH - 1); }
__device__ __forceinline__ int clampx(int v) { return min(max(v, 0), NW - 1); }

__device__ __forceinline__ float4 L4(const float* __restrict__ p, int row, int i) {
    return ((const float4*)(p + (size_t)row * NW))[i];
}

__device__ __forceinline__ void unpack8(const float4& A, const float4& B, float* o) {
    o[0] = A.x; o[1] = A.y; o[2] = A.z; o[3] = A.w;
    o[4] = B.x; o[5] = B.y; o[6] = B.z; o[7] = B.w;
}

// XCD-affinity decode: linear wgid -> (b, strip) such that all strips of
// batch b land on XCD b%8 (assuming round-robin wgid%8 -> XCD dispatch).
// wgid = (b&7) + 8*strip + 256*(b>>3), strip in [0,32), b in [0,16).
__device__ __forceinline__ void decode_bid(int bid, int& b, int& strip) {
    b = (bid & 7) + ((bid >> 8) << 3);
    strip = (bid >> 3) & 31;
}

__global__ __launch_bounds__(64) void gn_init(const float* __restrict__ p_in,
                                              float* __restrict__ pws,
                                              float* __restrict__ errws) {
    int t = threadIdx.x;
    if (t < 2 * NB) pws[t] = p_in[t];
    if (t == 0) errws[0] = 1e10f;
}

// Wave-private rows: each wave owns RPW full rows; zero barriers in main loop.
// Lane covers 8 cols; V kept in a per-wave LDS row with replicated-edge halo.
__global__ __launch_bounds__(NTHREADS) void gn_reduce(const float* __restrict__ I1,
                                                      const float* __restrict__ I2,
                                                      const float* __restrict__ pws,
                                                      double* __restrict__ partials) {
    int b, strip;
    decode_bid(blockIdx.x, b, strip);
    const int tid = threadIdx.x;
    const int wv = tid >> 6, lane = tid & 63;
    const int c0 = 8 * lane;
    const float tx = pws[2 * b];
    const float ty = pws[2 * b + 1];
    const float* I1b = I1 + (size_t)b * NHW;
    const float* I2b = I2 + (size_t)b * NHW;

    // ---- horizontal setup: weights once per lane, exact per-col floor check ----
    float gx0 = (float)c0 + tx;
    float fx0 = floorf(gx0);
    float dx0 = gx0 - fx0;
    int x00 = (int)fx0;
    const float wx0 = cubicf(dx0 + 1.0f), wx1 = cubicf(dx0);
    const float wx2 = cubicf(dx0 - 1.0f), wx3 = cubicf(dx0 - 2.0f);
    bool fast = true;
#pragma unroll
    for (int j = 1; j < 8; ++j) {
        int xj = (int)floorf((float)(c0 + j) + tx);
        fast = fast && (xj == x00 + j);
    }
    const int base = x00 - 1;                 // taps span base..base+10
    fast = fast && (base >= -8) && (base + 10 <= NW + 7);   // inside halo
    const int s = base & 3;
    const int wbase = base - s;               // 4-aligned

    __shared__ float VS[4][NW + 24];          // [wave][8 halo | 512 | 8 halo | pad]
    float* Vw = VS[wv];

    const int ybase = strip * ROWS + wv * RPW;

    // vertical taps for first row
    int yj0, yj1, yj2, yj3;
    {
        int yy = (int)floorf((float)ybase + ty);
        yj0 = clampy(yy - 1); yj1 = clampy(yy);
        yj2 = clampy(yy + 1); yj3 = clampy(yy + 2);
    }
    float4 w0a = L4(I2b, yj0, 2 * lane), w0b = L4(I2b, yj0, 2 * lane + 1);
    float4 w1a = L4(I2b, yj1, 2 * lane), w1b = L4(I2b, yj1, 2 * lane + 1);
    float4 w2a = L4(I2b, yj2, 2 * lane), w2b = L4(I2b, yj2, 2 * lane + 1);
    float4 w3a = L4(I2b, yj3, 2 * lane), w3b = L4(I2b, yj3, 2 * lane + 1);

    // I1 rolling rows
    float4 cpa = L4(I1b, max(ybase - 1, 0), 2 * lane), cpb = L4(I1b, max(ybase - 1, 0), 2 * lane + 1);
    float4 cca = L4(I1b, ybase, 2 * lane),             ccb = L4(I1b, ybase, 2 * lane + 1);
    float4 cna = L4(I1b, min(ybase + 1, NH - 1), 2 * lane), cnb = L4(I1b, min(ybase + 1, NH - 1), 2 * lane + 1);

    float a0 = 0.f, a1 = 0.f, a2 = 0.f, a3 = 0.f, a4 = 0.f;

#pragma unroll
    for (int r = 0; r < RPW; ++r) {
        const int y = ybase + r;

        // wy weights (per-lane, redundant, no LDS)
        float gy = (float)y + ty, fy = floorf(gy), dy = gy - fy;
        const float wy0 = cubicf(dy + 1.0f), wy1 = cubicf(dy);
        const float wy2 = cubicf(dy - 1.0f), wy3 = cubicf(dy - 2.0f);

        // next-row taps + prefetch (issued early, consumed at roll)
        int nyj0 = 0, nyj1 = 0, nyj2 = 0, nyj3 = 0;
        bool aligned = true;
        float4 nta, ntb, n1a, n1b;
        if (r + 1 < RPW) {
            int yy2 = (int)floorf((float)(y + 1) + ty);
            nyj0 = clampy(yy2 - 1); nyj1 = clampy(yy2);
            nyj2 = clampy(yy2 + 1); nyj3 = clampy(yy2 + 2);
            aligned = (nyj0 == yj1) && (nyj1 == yj2) && (nyj2 == yj3);
            nta = L4(I2b, nyj3, 2 * lane); ntb = L4(I2b, nyj3, 2 * lane + 1);
            n1a = L4(I1b, min(y + 2, NH - 1), 2 * lane);
            n1b = L4(I1b, min(y + 2, NH - 1), 2 * lane + 1);
        }

        // vertical combine -> wave-private LDS (+ halo)
        float4 Va, Vb;
        Va.x = wy0 * w0a.x + wy1 * w1a.x + wy2 * w2a.x + wy3 * w3a.x;
        Va.y = wy0 * w0a.y + wy1 * w1a.y + wy2 * w2a.y + wy3 * w3a.y;
        Va.z = wy0 * w0a.z + wy1 * w1a.z + wy2 * w2a.z + wy3 * w3a.z;
        Va.w = wy0 * w0a.w + wy1 * w1a.w + wy2 * w2a.w + wy3 * w3a.w;
        Vb.x = wy0 * w0b.x + wy1 * w1b.x + wy2 * w2b.x + wy3 * w3b.x;
        Vb.y = wy0 * w0b.y + wy1 * w1b.y + wy2 * w2b.y + wy3 * w3b.y;
        Vb.z = wy0 * w0b.z + wy1 * w1b.z + wy2 * w2b.z + wy3 * w3b.z;
        Vb.w = wy0 * w0b.w + wy1 * w1b.w + wy2 * w2b.w + wy3 * w3b.w;
        ((float4*)(Vw + 8))[2 * lane] = Va;
        ((float4*)(Vw + 8))[2 * lane + 1] = Vb;
        if (lane == 0)  { float4 h; h.x = h.y = h.z = h.w = Va.x; ((float4*)Vw)[0] = h; ((float4*)Vw)[1] = h; }
        if (lane == 63) { float4 h; h.x = h.y = h.z = h.w = Vb.w; ((float4*)(Vw + 8 + NW))[0] = h; ((float4*)(Vw + 8 + NW))[1] = h; }

        // I1 gradients (registers + in-wave shfl; row edges are wave edges)
        float left = __shfl_up(ccb.w, 1);
        float right = __shfl_down(cca.x, 1);
        float cc[8], cp[8], cn[8];
        unpack8(cca, ccb, cc); unpack8(cpa, cpb, cp); unpack8(cna, cnb, cn);
        float Ix[8], Iy[8];
        Ix[0] = (lane > 0) ? 0.5f * (cc[1] - left) : 0.0f;
#pragma unroll
        for (int j = 1; j < 7; ++j) Ix[j] = 0.5f * (cc[j + 1] - cc[j - 1]);
        Ix[7] = (lane < 63) ? 0.5f * (right - cc[6]) : 0.0f;
        const bool yint = (y >= 1 && y <= NH - 2);
#pragma unroll
        for (int j = 0; j < 8; ++j) Iy[j] = yint ? 0.5f * (cn[j] - cp[j]) : 0.0f;

        // horizontal pass (same-wave LDS round-trip, lgkmcnt only)
        float Hc[8];
        if (fast) {
            const float4* Wp = (const float4*)(Vw + 8 + wbase);
            float4 W0 = Wp[0], W1 = Wp[1], W2 = Wp[2], W3 = Wp[3];
            float u0, u1, u2, u3, u4, u5, u6, u7, u8, u9, u10;
            switch (s) {
                case 0:  u0=W0.x; u1=W0.y; u2=W0.z; u3=W0.w; u4=W1.x; u5=W1.y; u6=W1.z; u7=W1.w; u8=W2.x; u9=W2.y; u10=W2.z; break;
                case 1:  u0=W0.y; u1=W0.z; u2=W0.w; u3=W1.x; u4=W1.y; u5=W1.z; u6=W1.w; u7=W2.x; u8=W2.y; u9=W2.z; u10=W2.w; break;
                case 2:  u0=W0.z; u1=W0.w; u2=W1.x; u3=W1.y; u4=W1.z; u5=W1.w; u6=W2.x; u7=W2.y; u8=W2.z; u9=W2.w; u10=W3.x; break;
                default: u0=W0.w; u1=W1.x; u2=W1.y; u3=W1.z; u4=W1.w; u5=W2.x; u6=W2.y; u7=W2.z; u8=W2.w; u9=W3.x; u10=W3.y; break;
            }
            Hc[0] = wx0*u0 + wx1*u1 + wx2*u2  + wx3*u3;
            Hc[1] = wx0*u1 + wx1*u2 + wx2*u3  + wx3*u4;
            Hc[2] = wx0*u2 + wx1*u3 + wx2*u4  + wx3*u5;
            Hc[3] = wx0*u3 + wx1*u4 + wx2*u5  + wx3*u6;
            Hc[4] = wx0*u4 + wx1*u5 + wx2*u6  + wx3*u7;
            Hc[5] = wx0*u5 + wx1*u6 + wx2*u7  + wx3*u8;
            Hc[6] = wx0*u6 + wx1*u7 + wx2*u8  + wx3*u9;
            Hc[7] = wx0*u7 + wx1*u8 + wx2*u9  + wx3*u10;
        } else {
            // exact per-col slow path (floor-flip lanes; rare)
#pragma unroll
            for (int j = 0; j < 8; ++j) {
                float g = (float)(c0 + j) + tx;
                float f = floorf(g);
                int x0 = (int)f;
                float d = g - f;
                float v0 = cubicf(d + 1.0f), v1 = cubicf(d);
                float v2 = cubicf(d - 1.0f), v3 = cubicf(d - 2.0f);
                Hc[j] = v0 * Vw[8 + clampx(x0 - 1)] + v1 * Vw[8 + clampx(x0)] +
                        v2 * Vw[8 + clampx(x0 + 1)] + v3 * Vw[8 + clampx(x0 + 2)];
            }
        }

        // robust stats (f32 inner accumulation, widened at reduce)
#pragma unroll
        for (int j = 0; j < 8; ++j) {
            float DI = Hc[j] - cc[j];
            float rho = 1.0f / sqrtf(DI * DI + LAM2);
            float dr = DI * rho;
            a0 += Ix[j] * Ix[j] * rho;
            a1 += Ix[j] * Iy[j] * rho;
            a2 += Iy[j] * Iy[j] * rho;
            a3 += Ix[j] * dr;
            a4 += Iy[j] * dr;
        }

        // roll windows
        if (r + 1 < RPW) {
            if (aligned) {
                w0a = w1a; w0b = w1b; w1a = w2a; w1b = w2b; w2a = w3a; w2b = w3b;
            } else {          // border strips only
                w0a = L4(I2b, nyj0, 2 * lane); w0b = L4(I2b, nyj0, 2 * lane + 1);
                w1a = L4(I2b, nyj1, 2 * lane); w1b = L4(I2b, nyj1, 2 * lane + 1);
                w2a = L4(I2b, nyj2, 2 * lane); w2b = L4(I2b, nyj2, 2 * lane + 1);
            }
            w3a = nta; w3b = ntb;
            yj0 = nyj0; yj1 = nyj1; yj2 = nyj2; yj3 = nyj3;
            cpa = cca; cpb = ccb; cca = cna; ccb = cnb; cna = n1a; cnb = n1b;
        }
    }

    // widen to f64, wave butterfly, cross-wave via LDS (single barrier)
    double d0 = a0, d1 = a1, d2 = a2, d3 = a3, d4 = a4;
#pragma unroll
    for (int off = 32; off > 0; off >>= 1) {
        d0 += __shfl_down(d0, off);
        d1 += __shfl_down(d1, off);
        d2 += __shfl_down(d2, off);
        d3 += __shfl_down(d3, off);
        d4 += __shfl_down(d4, off);
    }
    __shared__ double wsum[4][5];
    if (lane == 0) {
        wsum[wv][0] = d0; wsum[wv][1] = d1; wsum[wv][2] = d2;
        wsum[wv][3] = d3; wsum[wv][4] = d4;
    }
    __syncthreads();
    if (tid < 5) {
        double ssum = wsum[0][tid] + wsum[1][tid] + wsum[2][tid] + wsum[3][tid];
        partials[(size_t)tid * COMP_STRIDE + b * NCHUNK + strip] = ssum;
    }
}

__global__ __launch_bounds__(128) void gn_update(const double* __restrict__ partials,
                                                 float* __restrict__ pws,
                                                 float* __restrict__ errws,
                                                 float* __restrict__ out,
                                                 int write_out) {
    __shared__ double Hs[NB][5];
    __shared__ float dpf[NB][2];
    __shared__ float pnew[2 * NB];
    const int tid = threadIdx.x;

    if (tid < NB * 5) {
        int bb = tid & 15, comp = tid >> 4;
        const double* src = partials + (size_t)comp * COMP_STRIDE + bb * NCHUNK;
        double s = 0;
#pragma unroll 8
        for (int ch = 0; ch < NCHUNK; ++ch) s += src[ch];
        Hs[bb][comp] = s;
    }
    __syncthreads();

    if (tid < NB) {
        double H00 = Hs[tid][0], H01 = Hs[tid][1], H11 = Hs[tid][2];
        double b0 = Hs[tid][3], b1 = Hs[tid][4];
        double inv = 1.0 / (H00 * H11 - H01 * H01);
        double dp0 = ( H11 * b0 - H01 * b1) * inv;
        double dp1 = (-H01 * b0 + H00 * b1) * inv;
        dpf[tid][0] = (float)dp0;
        dpf[tid][1] = (float)dp1;
    }
    __syncthreads();

    float err_old = errws[0];
    bool active = err_old > TOLV;

    if (tid < 2 * NB) {
        float pv = pws[tid];
        if (active) pv -= dpf[tid >> 1][tid & 1];
        pnew[tid] = pv;
        pws[tid] = pv;
    }

    float err_new = err_old;
    if (tid == 0) {
        if (active) {
            double n = 0;
            for (int i = 0; i < NB; ++i) {
                n += (double)dpf[i][0] * (double)dpf[i][0];
                n += (double)dpf[i][1] * (double)dpf[i][1];
            }
            err_new = (float)sqrt(n);
            errws[0] = err_new;
        }
    }
    __syncthreads();
    if (write_out) {
        if (tid < 2 * NB) out[tid] = pnew[tid];
        if (tid == 0) out[2 * NB] = err_new;
    }
}

// Barrier-free final warp: same structure, no stats, float4 stores.
__global__ __launch_bounds__(NTHREADS) void gn_final(const float* __restrict__ I1,
                                                     const float* __restrict__ I2,
                                                     const float* __restrict__ pws,
                                                     float* __restrict__ out) {
    int b, strip;
    decode_bid(blockIdx.x, b, strip);
    const int tid = threadIdx.x;
    const int wv = tid >> 6, lane = tid & 63;
    const int c0 = 8 * lane;
    const float tx = pws[2 * b];
    const float ty = pws[2 * b + 1];
    const float* I1b = I1 + (size_t)b * NHW;
    const float* I2b = I2 + (size_t)b * NHW;

    float* DIout = out + 33;
    float* IWout = out + 33 + (size_t)NB * NHW;

    float gx0 = (float)c0 + tx;
    float fx0 = floorf(gx0);
    float dx0 = gx0 - fx0;
    int x00 = (int)fx0;
    const float wx0 = cubicf(dx0 + 1.0f), wx1 = cubicf(dx0);
    const float wx2 = cubicf(dx0 - 1.0f), wx3 = cubicf(dx0 - 2.0f);
    bool fast = true;
#pragma unroll
    for (int j = 1; j < 8; ++j) {
        int xj = (int)floorf((float)(c0 + j) + tx);
        fast = fast && (xj == x00 + j);
    }
    const int base = x00 - 1;
    fast = fast && (base >= -8) && (base + 10 <= NW + 7);
    const int s = base & 3;
    const int wbase = base - s;

    __shared__ float VS[4][NW + 24];
    float* Vw = VS[wv];

    const int ybase = strip * ROWS + wv * RPW;

    int yj0, yj1, yj2, yj3;
    {
        int yy = (int)floorf((float)ybase + ty);
        yj0 = clampy(yy - 1); yj1 = clampy(yy);
        yj2 = clampy(yy + 1); yj3 = clampy(yy + 2);
    }
    float4 w0a = L4(I2b, yj0, 2 * lane), w0b = L4(I2b, yj0, 2 * lane + 1);
    float4 w1a = L4(I2b, yj1, 2 * lane), w1b = L4(I2b, yj1, 2 * lane + 1);
    float4 w2a = L4(I2b, yj2, 2 * lane), w2b = L4(I2b, yj2, 2 * lane + 1);
    float4 w3a = L4(I2b, yj3, 2 * lane), w3b = L4(I2b, yj3, 2 * lane + 1);
    float4 cca = L4(I1b, ybase, 2 * lane), ccb = L4(I1b, ybase, 2 * lane + 1);

#pragma unroll
    for (int r = 0; r < RPW; ++r) {
        const int y = ybase + r;

        float gy = (float)y + ty, fy = floorf(gy), dy = gy - fy;
        const float wy0 = cubicf(dy + 1.0f), wy1 = cubicf(dy);
        const float wy2 = cubicf(dy - 1.0f), wy3 = cubicf(dy - 2.0f);

        int nyj0 = 0, nyj1 = 0, nyj2 = 0, nyj3 = 0;
        bool aligned = true;
        float4 nta, ntb, n1a, n1b;
        if (r + 1 < RPW) {
            int yy2 = (int)floorf((float)(y + 1) + ty);
            nyj0 = clampy(yy2 - 1); nyj1 = clampy(yy2);
            nyj2 = clampy(yy2 + 1); nyj3 = clampy(yy2 + 2);
            aligned = (nyj0 == yj1) && (nyj1 == yj2) && (nyj2 == yj3);
            nta = L4(I2b, nyj3, 2 * lane); ntb = L4(I2b, nyj3, 2 * lane + 1);
            n1a = L4(I1b, y + 1, 2 * lane); n1b = L4(I1b, y + 1, 2 * lane + 1);
        }

        float4 Va, Vb;
        Va.x = wy0 * w0a.x + wy1 * w1a.x + wy2 * w2a.x + wy3 * w3a.x;
        Va.y = wy0 * w0a.y + wy1 * w1a.y + wy2 * w2a.y + wy3 * w3a.y;
        Va.z = wy0 * w0a.z + wy1 * w1a.z + wy2 * w2a.z + wy3 * w3a.z;
        Va.w = wy0 * w0a.w + wy1 * w1a.w + wy2 * w2a.w + wy3 * w3a.w;
        Vb.x = wy0 * w0b.x + wy1 * w1b.x + wy2 * w2b.x + wy3 * w3b.x;
        Vb.y = wy0 * w0b.y + wy1 * w1b.y + wy2 * w2b.y + wy3 * w3b.y;
        Vb.z = wy0 * w0b.z + wy1 * w1b.z + wy2 * w2b.z + wy3 * w3b.z;
        Vb.w = wy0 * w0b.w + wy1 * w1b.w + wy2 * w2b.w + wy3 * w3b.w;
        ((float4*)(Vw + 8))[2 * lane] = Va;
        ((float4*)(Vw + 8))[2 * lane + 1] = Vb;
        if (lane == 0)  { float4 h; h.x = h.y = h.z = h.w = Va.x; ((float4*)Vw)[0] = h; ((float4*)Vw)[1] = h; }
        if (lane == 63) { float4 h; h.x = h.y = h.z = h.w = Vb.w; ((float4*)(Vw + 8 + NW))[0] = h; ((float4*)(Vw + 8 + NW))[1] = h; }

        float Hc[8];
        if (fast) {
            const float4* Wp = (const float4*)(Vw + 8 + wbase);
            float4 W0 = Wp[0], W1 = Wp[1], W2 = Wp[2], W3 = Wp[3];
            float u0, u1, u2, u3, u4, u5, u6, u7, u8, u9, u10;
            switch (s) {
                case 0:  u0=W0.x; u1=W0.y; u2=W0.z; u3=W0.w; u4=W1.x; u5=W1.y; u6=W1.z; u7=W1.w; u8=W2.x; u9=W2.y; u10=W2.z; break;
                case 1:  u0=W0.y; u1=W0.z; u2=W0.w; u3=W1.x; u4=W1.y; u5=W1.z; u6=W1.w; u7=W2.x; u8=W2.y; u9=W2.z; u10=W2.w; break;
                case 2:  u0=W0.z; u1=W0.w; u2=W1.x; u3=W1.y; u4=W1.z; u5=W1.w; u6=W2.x; u7=W2.y; u8=W2.z; u9=W2.w; u10=W3.x; break;
                default: u0=W0.w; u1=W1.x; u2=W1.y; u3=W1.z; u4=W1.w; u5=W2.x; u6=W2.y; u7=W2.z; u8=W2.w; u9=W3.x; u10=W3.y; break;
            }
            Hc[0] = wx0*u0 + wx1*u1 + wx2*u2  + wx3*u3;
            Hc[1] = wx0*u1 + wx1*u2 + wx2*u3  + wx3*u4;
            Hc[2] = wx0*u2 + wx1*u3 + wx2*u4  + wx3*u5;
            Hc[3] = wx0*u3 + wx1*u4 + wx2*u5  + wx3*u6;
            Hc[4] = wx0*u4 + wx1*u5 + wx2*u6  + wx3*u7;
            Hc[5] = wx0*u5 + wx1*u6 + wx2*u7  + wx3*u8;
            Hc[6] = wx0*u6 + wx1*u7 + wx2*u8  + wx3*u9;
            Hc[7] = wx0*u7 + wx1*u8 + wx2*u9  + wx3*u10;
        } else {
#pragma unroll
            for (int j = 0; j < 8; ++j) {
                float g = (float)(c0 + j) + tx;
                float f = floorf(g);
                int x0 = (int)f;
                float d = g - f;
                float v0 = cubicf(d + 1.0f), v1 = cubicf(d);
                float v2 = cubicf(d - 1.0f), v3 = cubicf(d - 2.0f);
                Hc[j] = v0 * Vw[8 + clampx(x0 - 1)] + v1 * Vw[8 + clampx(x0)] +
                        v2 * Vw[8 + clampx(x0 + 1)] + v3 * Vw[8 + clampx(x0 + 2)];
            }
        }

        float cc[8];
        unpack8(cca, ccb, cc);
        float4 dA, dB, wA, wB;
        dA.x = Hc[0] - cc[0]; dA.y = Hc[1] - cc[1]; dA.z = Hc[2] - cc[2]; dA.w = Hc[3] - cc[3];
        dB.x = Hc[4] - cc[4]; dB.y = Hc[5] - cc[5]; dB.z = Hc[6] - cc[6]; dB.w = Hc[7] - cc[7];
        wA.x = Hc[0]; wA.y = Hc[1]; wA.z = Hc[2]; wA.w = Hc[3];
        wB.x = Hc[4]; wB.y = Hc[5]; wB.z = Hc[6]; wB.w = Hc[7];
        size_t o = (size_t)b * NHW + (size_t)y * NW + c0;
        *(float4*)(DIout + o) = dA; *(float4*)(DIout + o + 4) = dB;
        *(float4*)(IWout + o) = wA; *(float4*)(IWout + o + 4) = wB;

        if (r + 1 < RPW) {
            if (aligned) {
                w0a = w1a; w0b = w1b; w1a = w2a; w1b = w2b; w2a = w3a; w2b = w3b;
            } else {
                w0a = L4(I2b, nyj0, 2 * lane); w0b = L4(I2b, nyj0, 2 * lane + 1);
                w1a = L4(I2b, nyj1, 2 * lane); w1b = L4(I2b, nyj1, 2 * lane + 1);
                w2a = L4(I2b, nyj2, 2 * lane); w2b = L4(I2b, nyj2, 2 * lane + 1);
            }
            w3a = nta; w3b = ntb;
            yj0 = nyj0; yj1 = nyj1; yj2 = nyj2; yj3 = nyj3;
            cca = n1a; ccb = n1b;
        }
    }
}

extern "C" void kernel_launch(void* const* d_in, const int* in_sizes, int n_in,
                              void* d_out, int out_size, void* d_ws, size_t ws_size,
                              hipStream_t stream) {
    const float* I1 = (const float*)d_in[0];
    const float* I2 = (const float*)d_in[1];
    const float* p  = (const float*)d_in[2];
    float* out = (float*)d_out;

    double* partials = (double*)d_ws;
    float* pws   = (float*)((char*)d_ws + PWS_OFF);
    float* errws = (float*)((char*)d_ws + ERR_OFF);

    gn_init<<<1, 64, 0, stream>>>(p, pws, errws);

    const int nblk = NCHUNK * NB;   // 512, 1D grid with XCD-affinity encoding
    for (int t = 0; t < MAXIT; ++t) {
        gn_reduce<<<nblk, NTHREADS, 0, stream>>>(I1, I2, pws, partials);
        gn_update<<<1, 128, 0, stream>>>(partials, pws, errws, out, (t == MAXIT - 1) ? 1 : 0);
    }
    gn_final<<<nblk, NTHREADS, 0, stream>>>(I1, I2, pws, out);
}

// Round 13
// 160.344 us; speedup vs baseline: 1.4122x; 1.1315x over previous
//
#include <hip/hip_runtime.h>
#include <math.h>

#define NB 16
#define NH 512
#define NW 512
#define NHW (NH * NW)
#define LAM2 0.01f
#define TOLV 0.001f
#define MAXIT 10
#define ROWS 16                 // rows per block strip
#define RPW 4                   // rows per wave (4 waves/block)
#define NCHUNK (NH / ROWS)      // 32 strips per batch
#define NTHREADS 256
#define COMP_STRIDE (NB * NCHUNK)   // 512
#define NBLK (NB * NCHUNK)          // 512 blocks

// ws: partials double[2][5][512] then state float[2][34]
#define PARTIALS_SLOT (5 * COMP_STRIDE)
#define STATE_OFF_BYTES (2 * PARTIALS_SLOT * 8)

__device__ __forceinline__ float cubicf(float t) {
    float a = fabsf(t);
    float a2 = a * a;
    float a3 = a2 * a;
    if (a <= 1.0f) return 1.5f * a3 - 2.5f * a2 + 1.0f;
    if (a < 2.0f)  return -0.5f * a3 + 2.5f * a2 - 4.0f * a + 2.0f;
    return 0.0f;
}

__device__ __forceinline__ int clampy(int v) { return min(max(v, 0), NH - 1); }
__device__ __forceinline__ int clampx(int v) { return min(max(v, 0), NW - 1); }

__device__ __forceinline__ float4 L4(const float* __restrict__ p, int row, int i) {
    return ((const float4*)(p + (size_t)row * NW))[i];
}

__device__ __forceinline__ void unpack8(const float4& A, const float4& B, float* o) {
    o[0] = A.x; o[1] = A.y; o[2] = A.z; o[3] = A.w;
    o[4] = B.x; o[5] = B.y; o[6] = B.z; o[7] = B.w;
}

// XCD-affinity decode: all strips of batch b land on XCD b%8.
__device__ __forceinline__ void decode_bid(int bid, int& b, int& strip) {
    b = (bid & 7) + ((bid >> 8) << 3);
    strip = (bid >> 3) & 31;
}

// Redundant per-block GN update (prologue). Stream ordering between
// dispatches guarantees partials/state from dispatch t-1 are complete.
// All blocks compute bit-identical results (fixed summation order);
// duplicate state writes are benign.
__device__ __forceinline__ void do_update(int t, int b, int tid,
                                          const float* __restrict__ p_in,
                                          const double* __restrict__ partials,
                                          float* __restrict__ state,
                                          float& px, float& py, float& err_out) {
    if (t == 0) {
        px = p_in[2 * b]; py = p_in[2 * b + 1];
        err_out = 1e10f;
        if (tid < 32) state[tid] = p_in[tid];
        if (tid == 32) state[32] = 1e10f;
        return;
    }
    __shared__ double HsS[NB][5];
    __shared__ float dpfS[NB][2];
    __shared__ float pst[33];
    const double* src = partials + (size_t)((t - 1) & 1) * PARTIALS_SLOT;
    const float* stp = state + ((t - 1) & 1) * 34;
    float* stw = state + (t & 1) * 34;

    if (tid < 33) pst[tid] = stp[tid];
    if (tid < 80) {
        const double* q = src + 32 * tid;   // [comp][b][strip]: row = comp*16+b
        double s = 0;
#pragma unroll
        for (int ch = 0; ch < 32; ++ch) s += q[ch];
        HsS[tid & 15][tid >> 4] = s;
    }
    __syncthreads();
    if (tid < NB) {
        double H00 = HsS[tid][0], H01 = HsS[tid][1], H11 = HsS[tid][2];
        double b0 = HsS[tid][3], b1 = HsS[tid][4];
        double inv = 1.0 / (H00 * H11 - H01 * H01);
        dpfS[tid][0] = (float)(( H11 * b0 - H01 * b1) * inv);
        dpfS[tid][1] = (float)((-H01 * b0 + H00 * b1) * inv);
    }
    __syncthreads();
    float err_prev = pst[32];
    bool active = err_prev > TOLV;
    px = pst[2 * b]; py = pst[2 * b + 1];
    if (active) { px -= dpfS[b][0]; py -= dpfS[b][1]; }
    float err_new = err_prev;
    if (active) {
        double n = 0;
        for (int i = 0; i < NB; ++i) {
            n += (double)dpfS[i][0] * (double)dpfS[i][0];
            n += (double)dpfS[i][1] * (double)dpfS[i][1];
        }
        err_new = (float)sqrt(n);
    }
    err_out = err_new;
    if (tid < 32) {
        float v = pst[tid];
        if (active) v -= dpfS[tid >> 1][tid & 1];
        stw[tid] = v;
    }
    if (tid == 32) stw[32] = err_new;
    __syncthreads();
}

// Update prologue + wave-private reduce (R11 body). Writes partials[t&1].
__global__ __launch_bounds__(NTHREADS) void gn_step(const float* __restrict__ I1,
                                                    const float* __restrict__ I2,
                                                    const float* __restrict__ p_in,
                                                    double* __restrict__ partials,
                                                    float* __restrict__ state,
                                                    int t) {
    int b, strip;
    decode_bid(blockIdx.x, b, strip);
    const int tid = threadIdx.x;
    const int wv = tid >> 6, lane = tid & 63;
    const int c0 = 8 * lane;
    const float* I1b = I1 + (size_t)b * NHW;
    const float* I2b = I2 + (size_t)b * NHW;

    float px, py, errv;
    do_update(t, b, tid, p_in, partials, state, px, py, errv);
    const float tx = px, ty = py;

    float gx0 = (float)c0 + tx;
    float fx0 = floorf(gx0);
    float dx0 = gx0 - fx0;
    int x00 = (int)fx0;
    const float wx0 = cubicf(dx0 + 1.0f), wx1 = cubicf(dx0);
    const float wx2 = cubicf(dx0 - 1.0f), wx3 = cubicf(dx0 - 2.0f);
    bool fast = true;
#pragma unroll
    for (int j = 1; j < 8; ++j) {
        int xj = (int)floorf((float)(c0 + j) + tx);
        fast = fast && (xj == x00 + j);
    }
    const int base = x00 - 1;
    fast = fast && (base >= -8) && (base + 10 <= NW + 7);
    const int s = base & 3;
    const int wbase = base - s;

    __shared__ float VS[4][NW + 24];
    float* Vw = VS[wv];
    const int ybase = strip * ROWS + wv * RPW;

    int yj0, yj1, yj2, yj3;
    {
        int yy = (int)floorf((float)ybase + ty);
        yj0 = clampy(yy - 1); yj1 = clampy(yy);
        yj2 = clampy(yy + 1); yj3 = clampy(yy + 2);
    }
    float4 w0a = L4(I2b, yj0, 2 * lane), w0b = L4(I2b, yj0, 2 * lane + 1);
    float4 w1a = L4(I2b, yj1, 2 * lane), w1b = L4(I2b, yj1, 2 * lane + 1);
    float4 w2a = L4(I2b, yj2, 2 * lane), w2b = L4(I2b, yj2, 2 * lane + 1);
    float4 w3a = L4(I2b, yj3, 2 * lane), w3b = L4(I2b, yj3, 2 * lane + 1);

    float4 cpa = L4(I1b, max(ybase - 1, 0), 2 * lane), cpb = L4(I1b, max(ybase - 1, 0), 2 * lane + 1);
    float4 cca = L4(I1b, ybase, 2 * lane),             ccb = L4(I1b, ybase, 2 * lane + 1);
    float4 cna = L4(I1b, min(ybase + 1, NH - 1), 2 * lane), cnb = L4(I1b, min(ybase + 1, NH - 1), 2 * lane + 1);

    float a0 = 0.f, a1 = 0.f, a2 = 0.f, a3 = 0.f, a4 = 0.f;

#pragma unroll
    for (int r = 0; r < RPW; ++r) {
        const int y = ybase + r;

        float gy = (float)y + ty, fy = floorf(gy), dy = gy - fy;
        const float wy0 = cubicf(dy + 1.0f), wy1 = cubicf(dy);
        const float wy2 = cubicf(dy - 1.0f), wy3 = cubicf(dy - 2.0f);

        int nyj0 = 0, nyj1 = 0, nyj2 = 0, nyj3 = 0;
        bool aligned = true;
        float4 nta, ntb, n1a, n1b;
        if (r + 1 < RPW) {
            int yy2 = (int)floorf((float)(y + 1) + ty);
            nyj0 = clampy(yy2 - 1); nyj1 = clampy(yy2);
            nyj2 = clampy(yy2 + 1); nyj3 = clampy(yy2 + 2);
            aligned = (nyj0 == yj1) && (nyj1 == yj2) && (nyj2 == yj3);
            nta = L4(I2b, nyj3, 2 * lane); ntb = L4(I2b, nyj3, 2 * lane + 1);
            n1a = L4(I1b, min(y + 2, NH - 1), 2 * lane);
            n1b = L4(I1b, min(y + 2, NH - 1), 2 * lane + 1);
        }

        float4 Va, Vb;
        Va.x = wy0 * w0a.x + wy1 * w1a.x + wy2 * w2a.x + wy3 * w3a.x;
        Va.y = wy0 * w0a.y + wy1 * w1a.y + wy2 * w2a.y + wy3 * w3a.y;
        Va.z = wy0 * w0a.z + wy1 * w1a.z + wy2 * w2a.z + wy3 * w3a.z;
        Va.w = wy0 * w0a.w + wy1 * w1a.w + wy2 * w2a.w + wy3 * w3a.w;
        Vb.x = wy0 * w0b.x + wy1 * w1b.x + wy2 * w2b.x + wy3 * w3b.x;
        Vb.y = wy0 * w0b.y + wy1 * w1b.y + wy2 * w2b.y + wy3 * w3b.y;
        Vb.z = wy0 * w0b.z + wy1 * w1b.z + wy2 * w2b.z + wy3 * w3b.z;
        Vb.w = wy0 * w0b.w + wy1 * w1b.w + wy2 * w2b.w + wy3 * w3b.w;
        ((float4*)(Vw + 8))[2 * lane] = Va;
        ((float4*)(Vw + 8))[2 * lane + 1] = Vb;
        if (lane == 0)  { float4 h; h.x = h.y = h.z = h.w = Va.x; ((float4*)Vw)[0] = h; ((float4*)Vw)[1] = h; }
        if (lane == 63) { float4 h; h.x = h.y = h.z = h.w = Vb.w; ((float4*)(Vw + 8 + NW))[0] = h; ((float4*)(Vw + 8 + NW))[1] = h; }

        float left = __shfl_up(ccb.w, 1);
        float right = __shfl_down(cca.x, 1);
        float cc[8], cp[8], cn[8];
        unpack8(cca, ccb, cc); unpack8(cpa, cpb, cp); unpack8(cna, cnb, cn);
        float Ix[8], Iy[8];
        Ix[0] = (lane > 0) ? 0.5f * (cc[1] - left) : 0.0f;
#pragma unroll
        for (int j = 1; j < 7; ++j) Ix[j] = 0.5f * (cc[j + 1] - cc[j - 1]);
        Ix[7] = (lane < 63) ? 0.5f * (right - cc[6]) : 0.0f;
        const bool yint = (y >= 1 && y <= NH - 2);
#pragma unroll
        for (int j = 0; j < 8; ++j) Iy[j] = yint ? 0.5f * (cn[j] - cp[j]) : 0.0f;

        float Hc[8];
        if (fast) {
            const float4* Wp = (const float4*)(Vw + 8 + wbase);
            float4 W0 = Wp[0], W1 = Wp[1], W2 = Wp[2], W3 = Wp[3];
            float u0, u1, u2, u3, u4, u5, u6, u7, u8, u9, u10;
            switch (s) {
                case 0:  u0=W0.x; u1=W0.y; u2=W0.z; u3=W0.w; u4=W1.x; u5=W1.y; u6=W1.z; u7=W1.w; u8=W2.x; u9=W2.y; u10=W2.z; break;
                case 1:  u0=W0.y; u1=W0.z; u2=W0.w; u3=W1.x; u4=W1.y; u5=W1.z; u6=W1.w; u7=W2.x; u8=W2.y; u9=W2.z; u10=W2.w; break;
                case 2:  u0=W0.z; u1=W0.w; u2=W1.x; u3=W1.y; u4=W1.z; u5=W1.w; u6=W2.x; u7=W2.y; u8=W2.z; u9=W2.w; u10=W3.x; break;
                default: u0=W0.w; u1=W1.x; u2=W1.y; u3=W1.z; u4=W1.w; u5=W2.x; u6=W2.y; u7=W2.z; u8=W2.w; u9=W3.x; u10=W3.y; break;
            }
            Hc[0] = wx0*u0 + wx1*u1 + wx2*u2  + wx3*u3;
            Hc[1] = wx0*u1 + wx1*u2 + wx2*u3  + wx3*u4;
            Hc[2] = wx0*u2 + wx1*u3 + wx2*u4  + wx3*u5;
            Hc[3] = wx0*u3 + wx1*u4 + wx2*u5  + wx3*u6;
            Hc[4] = wx0*u4 + wx1*u5 + wx2*u6  + wx3*u7;
            Hc[5] = wx0*u5 + wx1*u6 + wx2*u7  + wx3*u8;
            Hc[6] = wx0*u6 + wx1*u7 + wx2*u8  + wx3*u9;
            Hc[7] = wx0*u7 + wx1*u8 + wx2*u9  + wx3*u10;
        } else {
#pragma unroll
            for (int j = 0; j < 8; ++j) {
                float g = (float)(c0 + j) + tx;
                float f = floorf(g);
                int x0 = (int)f;
                float d = g - f;
                float v0 = cubicf(d + 1.0f), v1 = cubicf(d);
                float v2 = cubicf(d - 1.0f), v3 = cubicf(d - 2.0f);
                Hc[j] = v0 * Vw[8 + clampx(x0 - 1)] + v1 * Vw[8 + clampx(x0)] +
                        v2 * Vw[8 + clampx(x0 + 1)] + v3 * Vw[8 + clampx(x0 + 2)];
            }
        }

#pragma unroll
        for (int j = 0; j < 8; ++j) {
            float DI = Hc[j] - cc[j];
            float rho = 1.0f / sqrtf(DI * DI + LAM2);
            float dr = DI * rho;
            a0 += Ix[j] * Ix[j] * rho;
            a1 += Ix[j] * Iy[j] * rho;
            a2 += Iy[j] * Iy[j] * rho;
            a3 += Ix[j] * dr;
            a4 += Iy[j] * dr;
        }

        if (r + 1 < RPW) {
            if (aligned) {
                w0a = w1a; w0b = w1b; w1a = w2a; w1b = w2b; w2a = w3a; w2b = w3b;
            } else {
                w0a = L4(I2b, nyj0, 2 * lane); w0b = L4(I2b, nyj0, 2 * lane + 1);
                w1a = L4(I2b, nyj1, 2 * lane); w1b = L4(I2b, nyj1, 2 * lane + 1);
                w2a = L4(I2b, nyj2, 2 * lane); w2b = L4(I2b, nyj2, 2 * lane + 1);
            }
            w3a = nta; w3b = ntb;
            yj0 = nyj0; yj1 = nyj1; yj2 = nyj2; yj3 = nyj3;
            cpa = cca; cpb = ccb; cca = cna; ccb = cnb; cna = n1a; cnb = n1b;
        }
    }

    double d0 = a0, d1 = a1, d2 = a2, d3 = a3, d4 = a4;
#pragma unroll
    for (int off = 32; off > 0; off >>= 1) {
        d0 += __shfl_down(d0, off);
        d1 += __shfl_down(d1, off);
        d2 += __shfl_down(d2, off);
        d3 += __shfl_down(d3, off);
        d4 += __shfl_down(d4, off);
    }
    __shared__ double wsum[4][5];
    if (lane == 0) {
        wsum[wv][0] = d0; wsum[wv][1] = d1; wsum[wv][2] = d2;
        wsum[wv][3] = d3; wsum[wv][4] = d4;
    }
    __syncthreads();
    double* pb = partials + (size_t)(t & 1) * PARTIALS_SLOT;
    if (tid < 5) {
        double ssum = wsum[0][tid] + wsum[1][tid] + wsum[2][tid] + wsum[3][tid];
        pb[(size_t)tid * COMP_STRIDE + b * NCHUNK + strip] = ssum;
    }
}

// Final: update step 9 (prologue) then warp pass with p_final.
__global__ __launch_bounds__(NTHREADS) void gn_final(const float* __restrict__ I1,
                                                     const float* __restrict__ I2,
                                                     const float* __restrict__ p_in,
                                                     double* __restrict__ partials,
                                                     float* __restrict__ state,
                                                     float* __restrict__ out) {
    int b, strip;
    decode_bid(blockIdx.x, b, strip);
    const int tid = threadIdx.x;
    const int wv = tid >> 6, lane = tid & 63;
    const int c0 = 8 * lane;
    const float* I1b = I1 + (size_t)b * NHW;
    const float* I2b = I2 + (size_t)b * NHW;

    float px, py, errv;
    do_update(MAXIT, b, tid, p_in, partials, state, px, py, errv);
    const float tx = px, ty = py;

    if (strip == 0 && tid == 0) { out[2 * b] = px; out[2 * b + 1] = py; }
    if (blockIdx.x == 0 && tid == 0) out[2 * NB] = errv;

    float* DIout = out + 33;
    float* IWout = out + 33 + (size_t)NB * NHW;

    float gx0 = (float)c0 + tx;
    float fx0 = floorf(gx0);
    float dx0 = gx0 - fx0;
    int x00 = (int)fx0;
    const float wx0 = cubicf(dx0 + 1.0f), wx1 = cubicf(dx0);
    const float wx2 = cubicf(dx0 - 1.0f), wx3 = cubicf(dx0 - 2.0f);
    bool fast = true;
#pragma unroll
    for (int j = 1; j < 8; ++j) {
        int xj = (int)floorf((float)(c0 + j) + tx);
        fast = fast && (xj == x00 + j);
    }
    const int base = x00 - 1;
    fast = fast && (base >= -8) && (base + 10 <= NW + 7);
    const int s = base & 3;
    const int wbase = base - s;

    __shared__ float VS[4][NW + 24];
    float* Vw = VS[wv];
    const int ybase = strip * ROWS + wv * RPW;

    int yj0, yj1, yj2, yj3;
    {
        int yy = (int)floorf((float)ybase + ty);
        yj0 = clampy(yy - 1); yj1 = clampy(yy);
        yj2 = clampy(yy + 1); yj3 = clampy(yy + 2);
    }
    float4 w0a = L4(I2b, yj0, 2 * lane), w0b = L4(I2b, yj0, 2 * lane + 1);
    float4 w1a = L4(I2b, yj1, 2 * lane), w1b = L4(I2b, yj1, 2 * lane + 1);
    float4 w2a = L4(I2b, yj2, 2 * lane), w2b = L4(I2b, yj2, 2 * lane + 1);
    float4 w3a = L4(I2b, yj3, 2 * lane), w3b = L4(I2b, yj3, 2 * lane + 1);
    float4 cca = L4(I1b, ybase, 2 * lane), ccb = L4(I1b, ybase, 2 * lane + 1);

#pragma unroll
    for (int r = 0; r < RPW; ++r) {
        const int y = ybase + r;

        float gy = (float)y + ty, fy = floorf(gy), dy = gy - fy;
        const float wy0 = cubicf(dy + 1.0f), wy1 = cubicf(dy);
        const float wy2 = cubicf(dy - 1.0f), wy3 = cubicf(dy - 2.0f);

        int nyj0 = 0, nyj1 = 0, nyj2 = 0, nyj3 = 0;
        bool aligned = true;
        float4 nta, ntb, n1a, n1b;
        if (r + 1 < RPW) {
            int yy2 = (int)floorf((float)(y + 1) + ty);
            nyj0 = clampy(yy2 - 1); nyj1 = clampy(yy2);
            nyj2 = clampy(yy2 + 1); nyj3 = clampy(yy2 + 2);
            aligned = (nyj0 == yj1) && (nyj1 == yj2) && (nyj2 == yj3);
            nta = L4(I2b, nyj3, 2 * lane); ntb = L4(I2b, nyj3, 2 * lane + 1);
            n1a = L4(I1b, y + 1, 2 * lane); n1b = L4(I1b, y + 1, 2 * lane + 1);
        }

        float4 Va, Vb;
        Va.x = wy0 * w0a.x + wy1 * w1a.x + wy2 * w2a.x + wy3 * w3a.x;
        Va.y = wy0 * w0a.y + wy1 * w1a.y + wy2 * w2a.y + wy3 * w3a.y;
        Va.z = wy0 * w0a.z + wy1 * w1a.z + wy2 * w2a.z + wy3 * w3a.z;
        Va.w = wy0 * w0a.w + wy1 * w1a.w + wy2 * w2a.w + wy3 * w3a.w;
        Vb.x = wy0 * w0b.x + wy1 * w1b.x + wy2 * w2b.x + wy3 * w3b.x;
        Vb.y = wy0 * w0b.y + wy1 * w1b.y + wy2 * w2b.y + wy3 * w3b.y;
        Vb.z = wy0 * w0b.z + wy1 * w1b.z + wy2 * w2b.z + wy3 * w3b.z;
        Vb.w = wy0 * w0b.w + wy1 * w1b.w + wy2 * w2b.w + wy3 * w3b.w;
        ((float4*)(Vw + 8))[2 * lane] = Va;
        ((float4*)(Vw + 8))[2 * lane + 1] = Vb;
        if (lane == 0)  { float4 h; h.x = h.y = h.z = h.w = Va.x; ((float4*)Vw)[0] = h; ((float4*)Vw)[1] = h; }
        if (lane == 63) { float4 h; h.x = h.y = h.z = h.w = Vb.w; ((float4*)(Vw + 8 + NW))[0] = h; ((float4*)(Vw + 8 + NW))[1] = h; }

        float Hc[8];
        if (fast) {
            const float4* Wp = (const float4*)(Vw + 8 + wbase);
            float4 W0 = Wp[0], W1 = Wp[1], W2 = Wp[2], W3 = Wp[3];
            float u0, u1, u2, u3, u4, u5, u6, u7, u8, u9, u10;
            switch (s) {
                case 0:  u0=W0.x; u1=W0.y; u2=W0.z; u3=W0.w; u4=W1.x; u5=W1.y; u6=W1.z; u7=W1.w; u8=W2.x; u9=W2.y; u10=W2.z; break;
                case 1:  u0=W0.y; u1=W0.z; u2=W0.w; u3=W1.x; u4=W1.y; u5=W1.z; u6=W1.w; u7=W2.x; u8=W2.y; u9=W2.z; u10=W2.w; break;
                case 2:  u0=W0.z; u1=W0.w; u2=W1.x; u3=W1.y; u4=W1.z; u5=W1.w; u6=W2.x; u7=W2.y; u8=W2.z; u9=W2.w; u10=W3.x; break;
                default: u0=W0.w; u1=W1.x; u2=W1.y; u3=W1.z; u4=W1.w; u5=W2.x; u6=W2.y; u7=W2.z; u8=W2.w; u9=W3.x; u10=W3.y; break;
            }
            Hc[0] = wx0*u0 + wx1*u1 + wx2*u2  + wx3*u3;
            Hc[1] = wx0*u1 + wx1*u2 + wx2*u3  + wx3*u4;
            Hc[2] = wx0*u2 + wx1*u3 + wx2*u4  + wx3*u5;
            Hc[3] = wx0*u3 + wx1*u4 + wx2*u5  + wx3*u6;
            Hc[4] = wx0*u4 + wx1*u5 + wx2*u6  + wx3*u7;
            Hc[5] = wx0*u5 + wx1*u6 + wx2*u7  + wx3*u8;
            Hc[6] = wx0*u6 + wx1*u7 + wx2*u8  + wx3*u9;
            Hc[7] = wx0*u7 + wx1*u8 + wx2*u9  + wx3*u10;
        } else {
#pragma unroll
            for (int j = 0; j < 8; ++j) {
                float g = (float)(c0 + j) + tx;
                float f = floorf(g);
                int x0 = (int)f;
                float d = g - f;
                float v0 = cubicf(d + 1.0f), v1 = cubicf(d);
                float v2 = cubicf(d - 1.0f), v3 = cubicf(d - 2.0f);
                Hc[j] = v0 * Vw[8 + clampx(x0 - 1)] + v1 * Vw[8 + clampx(x0)] +
                        v2 * Vw[8 + clampx(x0 + 1)] + v3 * Vw[8 + clampx(x0 + 2)];
            }
        }

        float cc[8];
        unpack8(cca, ccb, cc);
        float4 dA, dB, wA, wB;
        dA.x = Hc[0] - cc[0]; dA.y = Hc[1] - cc[1]; dA.z = Hc[2] - cc[2]; dA.w = Hc[3] - cc[3];
        dB.x = Hc[4] - cc[4]; dB.y = Hc[5] - cc[5]; dB.z = Hc[6] - cc[6]; dB.w = Hc[7] - cc[7];
        wA.x = Hc[0]; wA.y = Hc[1]; wA.z = Hc[2]; wA.w = Hc[3];
        wB.x = Hc[4]; wB.y = Hc[5]; wB.z = Hc[6]; wB.w = Hc[7];
        size_t o = (size_t)b * NHW + (size_t)y * NW + c0;
        *(float4*)(DIout + o) = dA; *(float4*)(DIout + o + 4) = dB;
        *(float4*)(IWout + o) = wA; *(float4*)(IWout + o + 4) = wB;

        if (r + 1 < RPW) {
            if (aligned) {
                w0a = w1a; w0b = w1b; w1a = w2a; w1b = w2b; w2a = w3a; w2b = w3b;
            } else {
                w0a = L4(I2b, nyj0, 2 * lane); w0b = L4(I2b, nyj0, 2 * lane + 1);
                w1a = L4(I2b, nyj1, 2 * lane); w1b = L4(I2b, nyj1, 2 * lane + 1);
                w2a = L4(I2b, nyj2, 2 * lane); w2b = L4(I2b, nyj2, 2 * lane + 1);
            }
            w3a = nta; w3b = ntb;
            yj0 = nyj0; yj1 = nyj1; yj2 = nyj2; yj3 = nyj3;
            cca = n1a; ccb = n1b;
        }
    }
}

extern "C" void kernel_launch(void* const* d_in, const int* in_sizes, int n_in,
                              void* d_out, int out_size, void* d_ws, size_t ws_size,
                              hipStream_t stream) {
    const float* I1 = (const float*)d_in[0];
    const float* I2 = (const float*)d_in[1];
    const float* p  = (const float*)d_in[2];
    float* out = (float*)d_out;
    double* partials = (double*)d_ws;
    float* state = (float*)((char*)d_ws + STATE_OFF_BYTES);

    for (int t = 0; t < MAXIT; ++t) {
        gn_step<<<NBLK, NTHREADS, 0, stream>>>(I1, I2, p, partials, state, t);
    }
    gn_final<<<NBLK, NTHREADS, 0, stream>>>(I1, I2, p, partials, state, out);
}

// Round 14
// 158.421 us; speedup vs baseline: 1.4293x; 1.0121x over previous
//
#include <hip/hip_runtime.h>
#include <math.h>

#define NB 16
#define NH 512
#define NW 512
#define NHW (NH * NW)
#define LAM2 0.01f
#define TOLV 0.001f
#define MAXIT 10
#define ROWS 16                 // rows per block strip
#define RPW 4                   // rows per wave (4 waves/block)
#define NCHUNK (NH / ROWS)      // 32 strips per batch
#define NTHREADS 256
#define COMP_STRIDE (NB * NCHUNK)   // 512
#define NBLK (NB * NCHUNK)          // 512 blocks

// ws: partials double[2][5][512] then state float[2][34]
#define PARTIALS_SLOT (5 * COMP_STRIDE)
#define STATE_OFF_BYTES (2 * PARTIALS_SLOT * 8)

__device__ __forceinline__ float cubicf(float t) {
    float a = fabsf(t);
    float a2 = a * a;
    float a3 = a2 * a;
    if (a <= 1.0f) return 1.5f * a3 - 2.5f * a2 + 1.0f;
    if (a < 2.0f)  return -0.5f * a3 + 2.5f * a2 - 4.0f * a + 2.0f;
    return 0.0f;
}

__device__ __forceinline__ int clampy(int v) { return min(max(v, 0), NH - 1); }
__device__ __forceinline__ int clampx(int v) { return min(max(v, 0), NW - 1); }

__device__ __forceinline__ float4 L4(const float* __restrict__ p, int row, int i) {
    return ((const float4*)(p + (size_t)row * NW))[i];
}

__device__ __forceinline__ void unpack8(const float4& A, const float4& B, float* o) {
    o[0] = A.x; o[1] = A.y; o[2] = A.z; o[3] = A.w;
    o[4] = B.x; o[5] = B.y; o[6] = B.z; o[7] = B.w;
}

// XCD-affinity decode: all strips of batch b land on XCD b%8.
__device__ __forceinline__ void decode_bid(int bid, int& b, int& strip) {
    b = (bid & 7) + ((bid >> 8) << 3);
    strip = (bid >> 3) & 31;
}

// Redundant per-block GN update (prologue). Stream ordering between
// dispatches guarantees partials/state from dispatch t-1 are complete.
// Coalesced LDS staging; ordered 32-element sums (bit-identical across blocks).
__device__ __forceinline__ void do_update(int t, int b, int tid,
                                          const float* __restrict__ p_in,
                                          const double* __restrict__ partials,
                                          float* __restrict__ state,
                                          float& px, float& py, float& err_out) {
    if (t == 0) {
        px = p_in[2 * b]; py = p_in[2 * b + 1];
        err_out = 1e10f;
        if (tid < 32) state[tid] = p_in[tid];
        if (tid == 32) state[32] = 1e10f;
        return;
    }
    __shared__ double US[80][33];
    __shared__ double HsS[NB][5];
    __shared__ float dpfS[NB][2];
    __shared__ float pst[33];
    const double* src = partials + (size_t)((t - 1) & 1) * PARTIALS_SLOT;
    const float* stp = state + ((t - 1) & 1) * 34;
    float* stw = state + (t & 1) * 34;

    // coalesced staging: 2560 doubles in 10 rounds of 256 contiguous loads
    double stg[10];
#pragma unroll
    for (int rnd = 0; rnd < 10; ++rnd) stg[rnd] = src[rnd * NTHREADS + tid];
    if (tid < 33) pst[tid] = stp[tid];
#pragma unroll
    for (int rnd = 0; rnd < 10; ++rnd) {
        int idx = rnd * NTHREADS + tid;
        US[idx >> 5][idx & 31] = stg[rnd];
    }
    __syncthreads();
    if (tid < 80) {
        double s = 0;
#pragma unroll
        for (int ch = 0; ch < 32; ++ch) s += US[tid][ch];
        HsS[tid & 15][tid >> 4] = s;      // Hs[batch][comp]
    }
    __syncthreads();
    if (tid < NB) {
        double H00 = HsS[tid][0], H01 = HsS[tid][1], H11 = HsS[tid][2];
        double b0 = HsS[tid][3], b1 = HsS[tid][4];
        double inv = 1.0 / (H00 * H11 - H01 * H01);
        dpfS[tid][0] = (float)(( H11 * b0 - H01 * b1) * inv);
        dpfS[tid][1] = (float)((-H01 * b0 + H00 * b1) * inv);
    }
    __syncthreads();
    float err_prev = pst[32];
    bool active = err_prev > TOLV;
    px = pst[2 * b]; py = pst[2 * b + 1];
    if (active) { px -= dpfS[b][0]; py -= dpfS[b][1]; }
    float err_new = err_prev;
    if (active) {
        double n = 0;
        for (int i = 0; i < NB; ++i) {
            n += (double)dpfS[i][0] * (double)dpfS[i][0];
            n += (double)dpfS[i][1] * (double)dpfS[i][1];
        }
        err_new = (float)sqrt(n);
    }
    err_out = err_new;
    if (tid < 32) {
        float v = pst[tid];
        if (active) v -= dpfS[tid >> 1][tid & 1];
        stw[tid] = v;
    }
    if (tid == 32) stw[32] = err_new;
    __syncthreads();
}

// Update prologue + wave-private reduce. Writes partials[t&1].
__global__ __launch_bounds__(NTHREADS) void gn_step(const float* __restrict__ I1,
                                                    const float* __restrict__ I2,
                                                    const float* __restrict__ p_in,
                                                    double* __restrict__ partials,
                                                    float* __restrict__ state,
                                                    int t) {
    int b, strip;
    decode_bid(blockIdx.x, b, strip);
    const int tid = threadIdx.x;
    const int wv = tid >> 6, lane = tid & 63;
    const int c0 = 8 * lane;
    const float* I1b = I1 + (size_t)b * NHW;
    const float* I2b = I2 + (size_t)b * NHW;

    __shared__ float VS[4][NW + 24];
    float* Vw = VS[wv];
    const int ybase = strip * ROWS + wv * RPW;

    // p-independent I1 window loads: issue BEFORE the update so their
    // latency overlaps the update's staging+solve.
    float4 cpa = L4(I1b, max(ybase - 1, 0), 2 * lane), cpb = L4(I1b, max(ybase - 1, 0), 2 * lane + 1);
    float4 cca = L4(I1b, ybase, 2 * lane),             ccb = L4(I1b, ybase, 2 * lane + 1);
    float4 cna = L4(I1b, min(ybase + 1, NH - 1), 2 * lane), cnb = L4(I1b, min(ybase + 1, NH - 1), 2 * lane + 1);

    float px, py, errv;
    do_update(t, b, tid, p_in, partials, state, px, py, errv);
    const float tx = px, ty = py;

    // converged: reduce result provably unused by next update (gate inactive)
    if (errv <= TOLV) return;

    float gx0 = (float)c0 + tx;
    float fx0 = floorf(gx0);
    float dx0 = gx0 - fx0;
    int x00 = (int)fx0;
    const float wx0 = cubicf(dx0 + 1.0f), wx1 = cubicf(dx0);
    const float wx2 = cubicf(dx0 - 1.0f), wx3 = cubicf(dx0 - 2.0f);
    bool fast = true;
#pragma unroll
    for (int j = 1; j < 8; ++j) {
        int xj = (int)floorf((float)(c0 + j) + tx);
        fast = fast && (xj == x00 + j);
    }
    const int base = x00 - 1;
    fast = fast && (base >= -8) && (base + 10 <= NW + 7);
    const int s = base & 3;
    const int wbase = base - s;

    int yj0, yj1, yj2, yj3;
    {
        int yy = (int)floorf((float)ybase + ty);
        yj0 = clampy(yy - 1); yj1 = clampy(yy);
        yj2 = clampy(yy + 1); yj3 = clampy(yy + 2);
    }
    float4 w0a = L4(I2b, yj0, 2 * lane), w0b = L4(I2b, yj0, 2 * lane + 1);
    float4 w1a = L4(I2b, yj1, 2 * lane), w1b = L4(I2b, yj1, 2 * lane + 1);
    float4 w2a = L4(I2b, yj2, 2 * lane), w2b = L4(I2b, yj2, 2 * lane + 1);
    float4 w3a = L4(I2b, yj3, 2 * lane), w3b = L4(I2b, yj3, 2 * lane + 1);

    float a0 = 0.f, a1 = 0.f, a2 = 0.f, a3 = 0.f, a4 = 0.f;

#pragma unroll
    for (int r = 0; r < RPW; ++r) {
        const int y = ybase + r;

        float gy = (float)y + ty, fy = floorf(gy), dy = gy - fy;
        const float wy0 = cubicf(dy + 1.0f), wy1 = cubicf(dy);
        const float wy2 = cubicf(dy - 1.0f), wy3 = cubicf(dy - 2.0f);

        int nyj0 = 0, nyj1 = 0, nyj2 = 0, nyj3 = 0;
        bool aligned = true;
        float4 nta, ntb, n1a, n1b;
        if (r + 1 < RPW) {
            int yy2 = (int)floorf((float)(y + 1) + ty);
            nyj0 = clampy(yy2 - 1); nyj1 = clampy(yy2);
            nyj2 = clampy(yy2 + 1); nyj3 = clampy(yy2 + 2);
            aligned = (nyj0 == yj1) && (nyj1 == yj2) && (nyj2 == yj3);
            nta = L4(I2b, nyj3, 2 * lane); ntb = L4(I2b, nyj3, 2 * lane + 1);
            n1a = L4(I1b, min(y + 2, NH - 1), 2 * lane);
            n1b = L4(I1b, min(y + 2, NH - 1), 2 * lane + 1);
        }

        float4 Va, Vb;
        Va.x = wy0 * w0a.x + wy1 * w1a.x + wy2 * w2a.x + wy3 * w3a.x;
        Va.y = wy0 * w0a.y + wy1 * w1a.y + wy2 * w2a.y + wy3 * w3a.y;
        Va.z = wy0 * w0a.z + wy1 * w1a.z + wy2 * w2a.z + wy3 * w3a.z;
        Va.w = wy0 * w0a.w + wy1 * w1a.w + wy2 * w2a.w + wy3 * w3a.w;
        Vb.x = wy0 * w0b.x + wy1 * w1b.x + wy2 * w2b.x + wy3 * w3b.x;
        Vb.y = wy0 * w0b.y + wy1 * w1b.y + wy2 * w2b.y + wy3 * w3b.y;
        Vb.z = wy0 * w0b.z + wy1 * w1b.z + wy2 * w2b.z + wy3 * w3b.z;
        Vb.w = wy0 * w0b.w + wy1 * w1b.w + wy2 * w2b.w + wy3 * w3b.w;
        ((float4*)(Vw + 8))[2 * lane] = Va;
        ((float4*)(Vw + 8))[2 * lane + 1] = Vb;
        if (lane == 0)  { float4 h; h.x = h.y = h.z = h.w = Va.x; ((float4*)Vw)[0] = h; ((float4*)Vw)[1] = h; }
        if (lane == 63) { float4 h; h.x = h.y = h.z = h.w = Vb.w; ((float4*)(Vw + 8 + NW))[0] = h; ((float4*)(Vw + 8 + NW))[1] = h; }

        float left = __shfl_up(ccb.w, 1);
        float right = __shfl_down(cca.x, 1);
        float cc[8], cp[8], cn[8];
        unpack8(cca, ccb, cc); unpack8(cpa, cpb, cp); unpack8(cna, cnb, cn);
        float Ix[8], Iy[8];
        Ix[0] = (lane > 0) ? 0.5f * (cc[1] - left) : 0.0f;
#pragma unroll
        for (int j = 1; j < 7; ++j) Ix[j] = 0.5f * (cc[j + 1] - cc[j - 1]);
        Ix[7] = (lane < 63) ? 0.5f * (right - cc[6]) : 0.0f;
        const bool yint = (y >= 1 && y <= NH - 2);
#pragma unroll
        for (int j = 0; j < 8; ++j) Iy[j] = yint ? 0.5f * (cn[j] - cp[j]) : 0.0f;

        float Hc[8];
        if (fast) {
            const float4* Wp = (const float4*)(Vw + 8 + wbase);
            float4 W0 = Wp[0], W1 = Wp[1], W2 = Wp[2], W3 = Wp[3];
            float u0, u1, u2, u3, u4, u5, u6, u7, u8, u9, u10;
            switch (s) {
                case 0:  u0=W0.x; u1=W0.y; u2=W0.z; u3=W0.w; u4=W1.x; u5=W1.y; u6=W1.z; u7=W1.w; u8=W2.x; u9=W2.y; u10=W2.z; break;
                case 1:  u0=W0.y; u1=W0.z; u2=W0.w; u3=W1.x; u4=W1.y; u5=W1.z; u6=W1.w; u7=W2.x; u8=W2.y; u9=W2.z; u10=W2.w; break;
                case 2:  u0=W0.z; u1=W0.w; u2=W1.x; u3=W1.y; u4=W1.z; u5=W1.w; u6=W2.x; u7=W2.y; u8=W2.z; u9=W2.w; u10=W3.x; break;
                default: u0=W0.w; u1=W1.x; u2=W1.y; u3=W1.z; u4=W1.w; u5=W2.x; u6=W2.y; u7=W2.z; u8=W2.w; u9=W3.x; u10=W3.y; break;
            }
            Hc[0] = wx0*u0 + wx1*u1 + wx2*u2  + wx3*u3;
            Hc[1] = wx0*u1 + wx1*u2 + wx2*u3  + wx3*u4;
            Hc[2] = wx0*u2 + wx1*u3 + wx2*u4  + wx3*u5;
            Hc[3] = wx0*u3 + wx1*u4 + wx2*u5  + wx3*u6;
            Hc[4] = wx0*u4 + wx1*u5 + wx2*u6  + wx3*u7;
            Hc[5] = wx0*u5 + wx1*u6 + wx2*u7  + wx3*u8;
            Hc[6] = wx0*u6 + wx1*u7 + wx2*u8  + wx3*u9;
            Hc[7] = wx0*u7 + wx1*u8 + wx2*u9  + wx3*u10;
        } else {
#pragma unroll
            for (int j = 0; j < 8; ++j) {
                float g = (float)(c0 + j) + tx;
                float f = floorf(g);
                int x0 = (int)f;
                float d = g - f;
                float v0 = cubicf(d + 1.0f), v1 = cubicf(d);
                float v2 = cubicf(d - 1.0f), v3 = cubicf(d - 2.0f);
                Hc[j] = v0 * Vw[8 + clampx(x0 - 1)] + v1 * Vw[8 + clampx(x0)] +
                        v2 * Vw[8 + clampx(x0 + 1)] + v3 * Vw[8 + clampx(x0 + 2)];
            }
        }

#pragma unroll
        for (int j = 0; j < 8; ++j) {
            float DI = Hc[j] - cc[j];
            float rho = 1.0f / sqrtf(DI * DI + LAM2);
            float dr = DI * rho;
            a0 += Ix[j] * Ix[j] * rho;
            a1 += Ix[j] * Iy[j] * rho;
            a2 += Iy[j] * Iy[j] * rho;
            a3 += Ix[j] * dr;
            a4 += Iy[j] * dr;
        }

        if (r + 1 < RPW) {
            if (aligned) {
                w0a = w1a; w0b = w1b; w1a = w2a; w1b = w2b; w2a = w3a; w2b = w3b;
            } else {
                w0a = L4(I2b, nyj0, 2 * lane); w0b = L4(I2b, nyj0, 2 * lane + 1);
                w1a = L4(I2b, nyj1, 2 * lane); w1b = L4(I2b, nyj1, 2 * lane + 1);
                w2a = L4(I2b, nyj2, 2 * lane); w2b = L4(I2b, nyj2, 2 * lane + 1);
            }
            w3a = nta; w3b = ntb;
            yj0 = nyj0; yj1 = nyj1; yj2 = nyj2; yj3 = nyj3;
            cpa = cca; cpb = ccb; cca = cna; ccb = cnb; cna = n1a; cnb = n1b;
        }
    }

    double d0 = a0, d1 = a1, d2 = a2, d3 = a3, d4 = a4;
#pragma unroll
    for (int off = 32; off > 0; off >>= 1) {
        d0 += __shfl_down(d0, off);
        d1 += __shfl_down(d1, off);
        d2 += __shfl_down(d2, off);
        d3 += __shfl_down(d3, off);
        d4 += __shfl_down(d4, off);
    }
    __shared__ double wsum[4][5];
    if (lane == 0) {
        wsum[wv][0] = d0; wsum[wv][1] = d1; wsum[wv][2] = d2;
        wsum[wv][3] = d3; wsum[wv][4] = d4;
    }
    __syncthreads();
    double* pb = partials + (size_t)(t & 1) * PARTIALS_SLOT;
    if (tid < 5) {
        double ssum = wsum[0][tid] + wsum[1][tid] + wsum[2][tid] + wsum[3][tid];
        pb[(size_t)tid * COMP_STRIDE + b * NCHUNK + strip] = ssum;
    }
}

// Final: update step 9 (prologue) then warp pass with p_final.
__global__ __launch_bounds__(NTHREADS) void gn_final(const float* __restrict__ I1,
                                                     const float* __restrict__ I2,
                                                     const float* __restrict__ p_in,
                                                     double* __restrict__ partials,
                                                     float* __restrict__ state,
                                                     float* __restrict__ out) {
    int b, strip;
    decode_bid(blockIdx.x, b, strip);
    const int tid = threadIdx.x;
    const int wv = tid >> 6, lane = tid & 63;
    const int c0 = 8 * lane;
    const float* I1b = I1 + (size_t)b * NHW;
    const float* I2b = I2 + (size_t)b * NHW;

    __shared__ float VS[4][NW + 24];
    float* Vw = VS[wv];
    const int ybase = strip * ROWS + wv * RPW;

    float4 cca = L4(I1b, ybase, 2 * lane), ccb = L4(I1b, ybase, 2 * lane + 1);

    float px, py, errv;
    do_update(MAXIT, b, tid, p_in, partials, state, px, py, errv);
    const float tx = px, ty = py;

    if (strip == 0 && tid == 0) { out[2 * b] = px; out[2 * b + 1] = py; }
    if (blockIdx.x == 0 && tid == 0) out[2 * NB] = errv;

    float* DIout = out + 33;
    float* IWout = out + 33 + (size_t)NB * NHW;

    float gx0 = (float)c0 + tx;
    float fx0 = floorf(gx0);
    float dx0 = gx0 - fx0;
    int x00 = (int)fx0;
    const float wx0 = cubicf(dx0 + 1.0f), wx1 = cubicf(dx0);
    const float wx2 = cubicf(dx0 - 1.0f), wx3 = cubicf(dx0 - 2.0f);
    bool fast = true;
#pragma unroll
    for (int j = 1; j < 8; ++j) {
        int xj = (int)floorf((float)(c0 + j) + tx);
        fast = fast && (xj == x00 + j);
    }
    const int base = x00 - 1;
    fast = fast && (base >= -8) && (base + 10 <= NW + 7);
    const int s = base & 3;
    const int wbase = base - s;

    int yj0, yj1, yj2, yj3;
    {
        int yy = (int)floorf((float)ybase + ty);
        yj0 = clampy(yy - 1); yj1 = clampy(yy);
        yj2 = clampy(yy + 1); yj3 = clampy(yy + 2);
    }
    float4 w0a = L4(I2b, yj0, 2 * lane), w0b = L4(I2b, yj0, 2 * lane + 1);
    float4 w1a = L4(I2b, yj1, 2 * lane), w1b = L4(I2b, yj1, 2 * lane + 1);
    float4 w2a = L4(I2b, yj2, 2 * lane), w2b = L4(I2b, yj2, 2 * lane + 1);
    float4 w3a = L4(I2b, yj3, 2 * lane), w3b = L4(I2b, yj3, 2 * lane + 1);

#pragma unroll
    for (int r = 0; r < RPW; ++r) {
        const int y = ybase + r;

        float gy = (float)y + ty, fy = floorf(gy), dy = gy - fy;
        const float wy0 = cubicf(dy + 1.0f), wy1 = cubicf(dy);
        const float wy2 = cubicf(dy - 1.0f), wy3 = cubicf(dy - 2.0f);

        int nyj0 = 0, nyj1 = 0, nyj2 = 0, nyj3 = 0;
        bool aligned = true;
        float4 nta, ntb, n1a, n1b;
        if (r + 1 < RPW) {
            int yy2 = (int)floorf((float)(y + 1) + ty);
            nyj0 = clampy(yy2 - 1); nyj1 = clampy(yy2);
            nyj2 = clampy(yy2 + 1); nyj3 = clampy(yy2 + 2);
            aligned = (nyj0 == yj1) && (nyj1 == yj2) && (nyj2 == yj3);
            nta = L4(I2b, nyj3, 2 * lane); ntb = L4(I2b, nyj3, 2 * lane + 1);
            n1a = L4(I1b, y + 1, 2 * lane); n1b = L4(I1b, y + 1, 2 * lane + 1);
        }

        float4 Va, Vb;
        Va.x = wy0 * w0a.x + wy1 * w1a.x + wy2 * w2a.x + wy3 * w3a.x;
        Va.y = wy0 * w0a.y + wy1 * w1a.y + wy2 * w2a.y + wy3 * w3a.y;
        Va.z = wy0 * w0a.z + wy1 * w1a.z + wy2 * w2a.z + wy3 * w3a.z;
        Va.w = wy0 * w0a.w + wy1 * w1a.w + wy2 * w2a.w + wy3 * w3a.w;
        Vb.x = wy0 * w0b.x + wy1 * w1b.x + wy2 * w2b.x + wy3 * w3b.x;
        Vb.y = wy0 * w0b.y + wy1 * w1b.y + wy2 * w2b.y + wy3 * w3b.y;
        Vb.z = wy0 * w0b.z + wy1 * w1b.z + wy2 * w2b.z + wy3 * w3b.z;
        Vb.w = wy0 * w0b.w + wy1 * w1b.w + wy2 * w2b.w + wy3 * w3b.w;
        ((float4*)(Vw + 8))[2 * lane] = Va;
        ((float4*)(Vw + 8))[2 * lane + 1] = Vb;
        if (lane == 0)  { float4 h; h.x = h.y = h.z = h.w = Va.x; ((float4*)Vw)[0] = h; ((float4*)Vw)[1] = h; }
        if (lane == 63) { float4 h; h.x = h.y = h.z = h.w = Vb.w; ((float4*)(Vw + 8 + NW))[0] = h; ((float4*)(Vw + 8 + NW))[1] = h; }

        float Hc[8];
        if (fast) {
            const float4* Wp = (const float4*)(Vw + 8 + wbase);
            float4 W0 = Wp[0], W1 = Wp[1], W2 = Wp[2], W3 = Wp[3];
            float u0, u1, u2, u3, u4, u5, u6, u7, u8, u9, u10;
            switch (s) {
                case 0:  u0=W0.x; u1=W0.y; u2=W0.z; u3=W0.w; u4=W1.x; u5=W1.y; u6=W1.z; u7=W1.w; u8=W2.x; u9=W2.y; u10=W2.z; break;
                case 1:  u0=W0.y; u1=W0.z; u2=W0.w; u3=W1.x; u4=W1.y; u5=W1.z; u6=W1.w; u7=W2.x; u8=W2.y; u9=W2.z; u10=W2.w; break;
                case 2:  u0=W0.z; u1=W0.w; u2=W1.x; u3=W1.y; u4=W1.z; u5=W1.w; u6=W2.x; u7=W2.y; u8=W2.z; u9=W2.w; u10=W3.x; break;
                default: u0=W0.w; u1=W1.x; u2=W1.y; u3=W1.z; u4=W1.w; u5=W2.x; u6=W2.y; u7=W2.z; u8=W2.w; u9=W3.x; u10=W3.y; break;
            }
            Hc[0] = wx0*u0 + wx1*u1 + wx2*u2  + wx3*u3;
            Hc[1] = wx0*u1 + wx1*u2 + wx2*u3  + wx3*u4;
            Hc[2] = wx0*u2 + wx1*u3 + wx2*u4  + wx3*u5;
            Hc[3] = wx0*u3 + wx1*u4 + wx2*u5  + wx3*u6;
            Hc[4] = wx0*u4 + wx1*u5 + wx2*u6  + wx3*u7;
            Hc[5] = wx0*u5 + wx1*u6 + wx2*u7  + wx3*u8;
            Hc[6] = wx0*u6 + wx1*u7 + wx2*u8  + wx3*u9;
            Hc[7] = wx0*u7 + wx1*u8 + wx2*u9  + wx3*u10;
        } else {
#pragma unroll
            for (int j = 0; j < 8; ++j) {
                float g = (float)(c0 + j) + tx;
                float f = floorf(g);
                int x0 = (int)f;
                float d = g - f;
                float v0 = cubicf(d + 1.0f), v1 = cubicf(d);
                float v2 = cubicf(d - 1.0f), v3 = cubicf(d - 2.0f);
                Hc[j] = v0 * Vw[8 + clampx(x0 - 1)] + v1 * Vw[8 + clampx(x0)] +
                        v2 * Vw[8 + clampx(x0 + 1)] + v3 * Vw[8 + clampx(x0 + 2)];
            }
        }

        float cc[8];
        unpack8(cca, ccb, cc);
        float4 dA, dB, wA, wB;
        dA.x = Hc[0] - cc[0]; dA.y = Hc[1] - cc[1]; dA.z = Hc[2] - cc[2]; dA.w = Hc[3] - cc[3];
        dB.x = Hc[4] - cc[4]; dB.y = Hc[5] - cc[5]; dB.z = Hc[6] - cc[6]; dB.w = Hc[7] - cc[7];
        wA.x = Hc[0]; wA.y = Hc[1]; wA.z = Hc[2]; wA.w = Hc[3];
        wB.x = Hc[4]; wB.y = Hc[5]; wB.z = Hc[6]; wB.w = Hc[7];
        size_t o = (size_t)b * NHW + (size_t)y * NW + c0;
        *(float4*)(DIout + o) = dA; *(float4*)(DIout + o + 4) = dB;
        *(float4*)(IWout + o) = wA; *(float4*)(IWout + o + 4) = wB;

        if (r + 1 < RPW) {
            if (aligned) {
                w0a = w1a; w0b = w1b; w1a = w2a; w1b = w2b; w2a = w3a; w2b = w3b;
            } else {
                w0a = L4(I2b, nyj0, 2 * lane); w0b = L4(I2b, nyj0, 2 * lane + 1);
                w1a = L4(I2b, nyj1, 2 * lane); w1b = L4(I2b, nyj1, 2 * lane + 1);
                w2a = L4(I2b, nyj2, 2 * lane); w2b = L4(I2b, nyj2, 2 * lane + 1);
            }
            w3a = nta; w3b = ntb;
            yj0 = nyj0; yj1 = nyj1; yj2 = nyj2; yj3 = nyj3;
            cca = n1a; ccb = n1b;
        }
    }
}

extern "C" void kernel_launch(void* const* d_in, const int* in_sizes, int n_in,
                              void* d_out, int out_size, void* d_ws, size_t ws_size,
                              hipStream_t stream) {
    const float* I1 = (const float*)d_in[0];
    const float* I2 = (const float*)d_in[1];
    const float* p  = (const float*)d_in[2];
    float* out = (float*)d_out;
    double* partials = (double*)d_ws;
    float* state = (float*)((char*)d_ws + STATE_OFF_BYTES);

    for (int t = 0; t < MAXIT; ++t) {
        gn_step<<<NBLK, NTHREADS, 0, stream>>>(I1, I2, p, partials, state, t);
    }
    gn_final<<<NBLK, NTHREADS, 0, stream>>>(I1, I2, p, partials, state, out);
}